// Round 1
// baseline (6101.474 us; speedup 1.0000x reference)
//
#include <hip/hip_runtime.h>
#include <math.h>

constexpr int B    = 4;
constexpr int NPTS = 4096;
constexpr int CIN  = 9;
constexpr int C0   = 18;
constexpr int KNB  = 8;
constexpr int HID  = 128;
constexpr int QB   = 4;     // queries per attention block
constexpr float EPSF = 1e-5f;

// ---------------- KNN + local diff features ----------------
// h0[b, c, n]: c in [0,9) = mean(neigh)-x ; c in [9,18) = x
__global__ __launch_bounds__(256) void knn_kernel(const float* __restrict__ x,
                                                  float* __restrict__ h0) {
    const int tid = threadIdx.x;
    const int gid = blockIdx.x * 256 + tid;
    const int b = gid >> 12;            // NPTS = 4096
    const int n = gid & (NPTS - 1);
    __shared__ float sx[256][3];
    const float* xb = x + (size_t)b * NPTS * CIN;
    const float qx = xb[n * CIN + 0];
    const float qy = xb[n * CIN + 1];
    const float qz = xb[n * CIN + 2];
    float bd[KNB];
    int   bi[KNB];
#pragma unroll
    for (int i = 0; i < KNB; ++i) { bd[i] = 3.0e38f; bi[i] = 0; }
    for (int t0 = 0; t0 < NPTS; t0 += 256) {
        __syncthreads();
        const int mload = t0 + tid;
        sx[tid][0] = xb[mload * CIN + 0];
        sx[tid][1] = xb[mload * CIN + 1];
        sx[tid][2] = xb[mload * CIN + 2];
        __syncthreads();
        for (int j = 0; j < 256; ++j) {
            const float dx = sx[j][0] - qx;
            const float dy = sx[j][1] - qy;
            const float dz = sx[j][2] - qz;
            const float d2 = dx * dx + dy * dy + dz * dz;
            const int m = t0 + j;
            if (d2 < bd[KNB - 1] && m != n) {
                bd[KNB - 1] = d2; bi[KNB - 1] = m;
#pragma unroll
                for (int p = KNB - 1; p > 0; --p) {
                    if (bd[p] < bd[p - 1]) {
                        float td = bd[p]; bd[p] = bd[p - 1]; bd[p - 1] = td;
                        int   ti = bi[p]; bi[p] = bi[p - 1]; bi[p - 1] = ti;
                    }
                }
            }
        }
    }
    float sums[CIN];
#pragma unroll
    for (int c = 0; c < CIN; ++c) sums[c] = 0.f;
    for (int k = 0; k < KNB; ++k) {
        const float* xp = xb + (size_t)bi[k] * CIN;
#pragma unroll
        for (int c = 0; c < CIN; ++c) sums[c] += xp[c];
    }
    const float inv = 1.0f / (float)KNB;
#pragma unroll
    for (int c = 0; c < CIN; ++c) {
        const float xv = xb[n * CIN + c];
        h0[((size_t)b * C0 + c) * NPTS + n]       = sums[c] * inv - xv;
        h0[((size_t)b * C0 + CIN + c) * NPTS + n] = xv;
    }
}

// ---------------- 1x1 conv (channel GEMM): Y[b,o,n] = sum_c W[o,c] X[b,c,n] + bias[o] ----------------
// grid: (NPTS/64, ceil(O/16), B), block 256.  thread: n = bx*64 + (tid&63), og = tid>>6 covers 4 o's.
template <bool RELU, bool RES>
__global__ __launch_bounds__(256) void conv_kernel(const float* __restrict__ X,
                                                   const float* __restrict__ W,
                                                   const float* __restrict__ bias,
                                                   const float* __restrict__ res,
                                                   float* __restrict__ Y,
                                                   int C, int O) {
    __shared__ float Ws[16 * 256];
    const int b  = blockIdx.z;
    const int o_base = blockIdx.y * 16;
    const int n  = blockIdx.x * 64 + (threadIdx.x & 63);
    const int og = threadIdx.x >> 6;
    const int rows = min(16, O - o_base);
    for (int i = threadIdx.x; i < rows * C; i += 256)
        Ws[i] = W[(size_t)o_base * C + i];
    __syncthreads();
    float acc[4] = {0.f, 0.f, 0.f, 0.f};
    const float* Xp = X + (size_t)b * C * NPTS + n;
    for (int c = 0; c < C; ++c) {
        const float xv = Xp[(size_t)c * NPTS];
#pragma unroll
        for (int i = 0; i < 4; ++i)
            acc[i] = fmaf(Ws[(og * 4 + i) * C + c], xv, acc[i]);
    }
#pragma unroll
    for (int i = 0; i < 4; ++i) {
        const int o = o_base + og * 4 + i;
        if (o < O) {
            float v = acc[i] + bias[o];
            if (RES)  v += res[((size_t)b * O + o) * NPTS + n];
            if (RELU) v = fmaxf(v, 0.f);
            Y[((size_t)b * O + o) * NPTS + n] = v;
        }
    }
}

// ---------------- BN statistics: per-channel mean / inv-std over (B, N) ----------------
__global__ __launch_bounds__(256) void bn_stats_kernel(const float* __restrict__ Y,
                                                       float* __restrict__ mean,
                                                       float* __restrict__ istd,
                                                       int O) {
    const int o = blockIdx.x;
    const int tid = threadIdx.x;
    __shared__ double rs[256];
    __shared__ double rs2[256];
    double s = 0.0, s2 = 0.0;
    for (int i = tid; i < B * NPTS; i += 256) {
        const int bb = i >> 12;
        const int nn = i & (NPTS - 1);
        const float v = Y[((size_t)bb * O + o) * NPTS + nn];
        s  += (double)v;
        s2 += (double)v * (double)v;
    }
    rs[tid] = s; rs2[tid] = s2;
    __syncthreads();
    for (int st = 128; st > 0; st >>= 1) {
        if (tid < st) { rs[tid] += rs[tid + st]; rs2[tid] += rs2[tid + st]; }
        __syncthreads();
    }
    if (tid == 0) {
        const double M = (double)(B * NPTS);
        const double m = rs[0] / M;
        const double var = rs2[0] / M - m * m;
        mean[o] = (float)m;
        istd[o] = (float)(1.0 / sqrt(var + (double)EPSF));
    }
}

// ---------------- BN apply + ReLU (in place) ----------------
__global__ __launch_bounds__(256) void bn_relu_kernel(float* __restrict__ Y,
                                                      const float* __restrict__ g,
                                                      const float* __restrict__ be,
                                                      const float* __restrict__ mean,
                                                      const float* __restrict__ istd,
                                                      int O) {
    const size_t total = (size_t)B * O * NPTS;
    for (size_t idx = (size_t)blockIdx.x * 256 + threadIdx.x; idx < total;
         idx += (size_t)gridDim.x * 256) {
        const int o = (int)((idx / NPTS) % O);
        float v = Y[idx];
        v = g[o] * (v - mean[o]) * istd[o] + be[o];
        Y[idx] = fmaxf(v, 0.f);
    }
}

// ---------------- attention: softmax(Q^T K) then O = V * P^T, 4 queries per block ----------------
__global__ __launch_bounds__(256) void attn_kernel(const float* __restrict__ Qg,
                                                   const float* __restrict__ Kg,
                                                   const float* __restrict__ Vg,
                                                   float* __restrict__ Og) {
    __shared__ float P[QB][NPTS];      // 64 KB
    __shared__ float Qs[QB][HID];
    __shared__ float red[256];
    __shared__ float smax[QB];
    __shared__ float ssum[QB];
    const int b   = blockIdx.y;
    const int q0  = blockIdx.x * QB;
    const int tid = threadIdx.x;
    const size_t base = (size_t)b * HID * NPTS;
    for (int i = tid; i < QB * HID; i += 256) {
        const int qi = i >> 7, h = i & (HID - 1);
        Qs[qi][h] = Qg[base + (size_t)h * NPTS + q0 + qi];
    }
    __syncthreads();
    // phase 1: scores + local max
    float lmq[QB];
#pragma unroll
    for (int qi = 0; qi < QB; ++qi) lmq[qi] = -3.0e38f;
    for (int m = tid; m < NPTS; m += 256) {
        const float* Kp = Kg + base + m;
        float s0 = 0.f, s1 = 0.f, s2 = 0.f, s3 = 0.f;
#pragma unroll 8
        for (int h = 0; h < HID; ++h) {
            const float kv = Kp[(size_t)h * NPTS];
            s0 = fmaf(Qs[0][h], kv, s0);
            s1 = fmaf(Qs[1][h], kv, s1);
            s2 = fmaf(Qs[2][h], kv, s2);
            s3 = fmaf(Qs[3][h], kv, s3);
        }
        P[0][m] = s0; P[1][m] = s1; P[2][m] = s2; P[3][m] = s3;
        lmq[0] = fmaxf(lmq[0], s0); lmq[1] = fmaxf(lmq[1], s1);
        lmq[2] = fmaxf(lmq[2], s2); lmq[3] = fmaxf(lmq[3], s3);
    }
#pragma unroll
    for (int qi = 0; qi < QB; ++qi) {
        red[tid] = lmq[qi];
        __syncthreads();
        for (int st = 128; st > 0; st >>= 1) {
            if (tid < st) red[tid] = fmaxf(red[tid], red[tid + st]);
            __syncthreads();
        }
        if (tid == 0) smax[qi] = red[0];
        __syncthreads();
    }
    // phase 2: exp + local sum
    float lsq[QB];
#pragma unroll
    for (int qi = 0; qi < QB; ++qi) lsq[qi] = 0.f;
    const float mx0 = smax[0], mx1 = smax[1], mx2 = smax[2], mx3 = smax[3];
    for (int m = tid; m < NPTS; m += 256) {
        float p0 = __expf(P[0][m] - mx0); P[0][m] = p0; lsq[0] += p0;
        float p1 = __expf(P[1][m] - mx1); P[1][m] = p1; lsq[1] += p1;
        float p2 = __expf(P[2][m] - mx2); P[2][m] = p2; lsq[2] += p2;
        float p3 = __expf(P[3][m] - mx3); P[3][m] = p3; lsq[3] += p3;
    }
#pragma unroll
    for (int qi = 0; qi < QB; ++qi) {
        red[tid] = lsq[qi];
        __syncthreads();
        for (int st = 128; st > 0; st >>= 1) {
            if (tid < st) red[tid] += red[tid + st];
            __syncthreads();
        }
        if (tid == 0) ssum[qi] = red[0];
        __syncthreads();
    }
    const float i0 = 1.f / ssum[0], i1 = 1.f / ssum[1];
    const float i2 = 1.f / ssum[2], i3 = 1.f / ssum[3];
    // phase 3: O[b,h,q] = sum_m P[q][m] * V[b,h,m]
    const int wave = tid >> 6, lane = tid & 63;
    for (int h = wave * 32; h < wave * 32 + 32; ++h) {
        const float* Vp = Vg + base + (size_t)h * NPTS;
        float a0 = 0.f, a1 = 0.f, a2 = 0.f, a3 = 0.f;
        for (int m = lane; m < NPTS; m += 64) {
            const float vv = Vp[m];
            a0 = fmaf(P[0][m], vv, a0);
            a1 = fmaf(P[1][m], vv, a1);
            a2 = fmaf(P[2][m], vv, a2);
            a3 = fmaf(P[3][m], vv, a3);
        }
#pragma unroll
        for (int off = 32; off > 0; off >>= 1) {
            a0 += __shfl_down(a0, off, 64);
            a1 += __shfl_down(a1, off, 64);
            a2 += __shfl_down(a2, off, 64);
            a3 += __shfl_down(a3, off, 64);
        }
        if (lane == 0) {
            Og[base + (size_t)h * NPTS + q0 + 0] = a0 * i0;
            Og[base + (size_t)h * NPTS + q0 + 1] = a1 * i1;
            Og[base + (size_t)h * NPTS + q0 + 2] = a2 * i2;
            Og[base + (size_t)h * NPTS + q0 + 3] = a3 * i3;
        }
    }
}

// ---------------- softmax over N of the pooling scores (in place) ----------------
__global__ __launch_bounds__(256) void softmax_w_kernel(float* __restrict__ s) {
    const int b = blockIdx.x;
    const int tid = threadIdx.x;
    __shared__ float red[256];
    float lm = -3.0e38f;
    for (int n = tid; n < NPTS; n += 256) lm = fmaxf(lm, s[b * NPTS + n]);
    red[tid] = lm;
    __syncthreads();
    for (int st = 128; st > 0; st >>= 1) {
        if (tid < st) red[tid] = fmaxf(red[tid], red[tid + st]);
        __syncthreads();
    }
    const float mx = red[0];
    __syncthreads();
    float ls = 0.f;
    for (int n = tid; n < NPTS; n += 256) {
        const float p = __expf(s[b * NPTS + n] - mx);
        s[b * NPTS + n] = p;
        ls += p;
    }
    red[tid] = ls;
    __syncthreads();
    for (int st = 128; st > 0; st >>= 1) {
        if (tid < st) red[tid] += red[tid + st];
        __syncthreads();
    }
    const float inv = 1.f / red[0];
    __syncthreads();
    for (int n = tid; n < NPTS; n += 256) s[b * NPTS + n] *= inv;
}

// ---------------- weighted pooling: pooled[b,c] = sum_n h[b,c,n] * w[b,n] ----------------
__global__ __launch_bounds__(256) void pool_kernel(const float* __restrict__ h,
                                                   const float* __restrict__ w,
                                                   float* __restrict__ pooled) {
    const int c = blockIdx.x, b = blockIdx.y, tid = threadIdx.x;
    __shared__ float red[256];
    const float* hp = h + ((size_t)b * 256 + c) * NPTS;
    const float* wp = w + (size_t)b * NPTS;
    float acc = 0.f;
    for (int n = tid; n < NPTS; n += 256) acc = fmaf(hp[n], wp[n], acc);
    red[tid] = acc;
    __syncthreads();
    for (int st = 128; st > 0; st >>= 1) {
        if (tid < st) red[tid] += red[tid + st];
        __syncthreads();
    }
    if (tid == 0) pooled[b * 256 + c] = red[0];
}

// ---------------- final FC + ReLU ----------------
__global__ __launch_bounds__(256) void fc_kernel(const float* __restrict__ pooled,
                                                 const float* __restrict__ fcw,
                                                 const float* __restrict__ fcb,
                                                 float* __restrict__ out) {
    const int b = blockIdx.x, j = threadIdx.x;
    __shared__ float ps[256];
    ps[j] = pooled[b * 256 + j];
    __syncthreads();
    float acc = fcb[j];
    for (int c = 0; c < 256; ++c) acc = fmaf(ps[c], fcw[j * 256 + c], acc);
    out[b * 256 + j] = fmaxf(acc, 0.f);
}

extern "C" void kernel_launch(void* const* d_in, const int* in_sizes, int n_in,
                              void* d_out, int out_size, void* d_ws, size_t ws_size,
                              hipStream_t stream) {
    const float* x   = (const float*)d_in[0];
    const float* w1  = (const float*)d_in[1];
    const float* b1  = (const float*)d_in[2];
    const float* g1  = (const float*)d_in[3];
    const float* be1 = (const float*)d_in[4];
    const float* w2  = (const float*)d_in[5];
    const float* b2  = (const float*)d_in[6];
    const float* g2  = (const float*)d_in[7];
    const float* be2 = (const float*)d_in[8];
    const float* w3  = (const float*)d_in[9];
    const float* b3  = (const float*)d_in[10];
    const float* g3  = (const float*)d_in[11];
    const float* be3 = (const float*)d_in[12];
    const float* qw  = (const float*)d_in[13];
    const float* qb  = (const float*)d_in[14];
    const float* kw  = (const float*)d_in[15];
    const float* kb  = (const float*)d_in[16];
    const float* vw  = (const float*)d_in[17];
    const float* vb  = (const float*)d_in[18];
    const float* fw  = (const float*)d_in[19];
    const float* fb  = (const float*)d_in[20];
    const float* aw1 = (const float*)d_in[21];
    const float* ab1 = (const float*)d_in[22];
    const float* aw2 = (const float*)d_in[23];
    const float* ab2 = (const float*)d_in[24];
    const float* fcw = (const float*)d_in[25];
    const float* fcb = (const float*)d_in[26];

    float* ws = (float*)d_ws;
    float* h0 = ws;                     // 4*18*4096   = 294912
    float* h1 = h0 + 294912;            // 4*64*4096   = 1048576
    float* h2 = h1 + 1048576;           // 4*128*4096  = 2097152
    float* h3 = h2 + 2097152;           // 4*256*4096  = 4194304
    float* Q  = h3 + 4194304;           // 2097152
    float* K  = Q  + 2097152;
    float* V  = K  + 2097152;
    float* Oa = V  + 2097152;
    float* h4 = Oa + 2097152;           // 4194304
    float* a  = h4 + 4194304;           // 1048576
    float* s  = a  + 1048576;           // 16384
    float* pooled = s + 16384;          // 1024
    float* mean   = pooled + 1024;      // 256
    float* istd   = mean + 256;         // 256

    knn_kernel<<<dim3(B * NPTS / 256), 256, 0, stream>>>(x, h0);

    // layer 1: 18 -> 64
    conv_kernel<false, false><<<dim3(NPTS / 64, 4, B), 256, 0, stream>>>(h0, w1, b1, nullptr, h1, C0, 64);
    bn_stats_kernel<<<64, 256, 0, stream>>>(h1, mean, istd, 64);
    bn_relu_kernel<<<2048, 256, 0, stream>>>(h1, g1, be1, mean, istd, 64);
    // layer 2: 64 -> 128
    conv_kernel<false, false><<<dim3(NPTS / 64, 8, B), 256, 0, stream>>>(h1, w2, b2, nullptr, h2, 64, 128);
    bn_stats_kernel<<<128, 256, 0, stream>>>(h2, mean, istd, 128);
    bn_relu_kernel<<<2048, 256, 0, stream>>>(h2, g2, be2, mean, istd, 128);
    // layer 3: 128 -> 256
    conv_kernel<false, false><<<dim3(NPTS / 64, 16, B), 256, 0, stream>>>(h2, w3, b3, nullptr, h3, 128, 256);
    bn_stats_kernel<<<256, 256, 0, stream>>>(h3, mean, istd, 256);
    bn_relu_kernel<<<2048, 256, 0, stream>>>(h3, g3, be3, mean, istd, 256);

    // Q, K, V projections: 256 -> 128
    conv_kernel<false, false><<<dim3(NPTS / 64, 8, B), 256, 0, stream>>>(h3, qw, qb, nullptr, Q, 256, 128);
    conv_kernel<false, false><<<dim3(NPTS / 64, 8, B), 256, 0, stream>>>(h3, kw, kb, nullptr, K, 256, 128);
    conv_kernel<false, false><<<dim3(NPTS / 64, 8, B), 256, 0, stream>>>(h3, vw, vb, nullptr, V, 256, 128);

    attn_kernel<<<dim3(NPTS / QB, B), 256, 0, stream>>>(Q, K, V, Oa);

    // fuse-out conv + residual: 128 -> 256, + h3
    conv_kernel<false, true><<<dim3(NPTS / 64, 16, B), 256, 0, stream>>>(Oa, fw, fb, h3, h4, 128, 256);
    // attention-pool MLP
    conv_kernel<true, false><<<dim3(NPTS / 64, 4, B), 256, 0, stream>>>(h4, aw1, ab1, nullptr, a, 256, 64);
    conv_kernel<false, false><<<dim3(NPTS / 64, 1, B), 256, 0, stream>>>(a, aw2, ab2, nullptr, s, 64, 1);

    softmax_w_kernel<<<B, 256, 0, stream>>>(s);
    pool_kernel<<<dim3(256, B), 256, 0, stream>>>(h4, s, pooled);
    fc_kernel<<<B, 256, 0, stream>>>(pooled, fcw, fcb, (float*)d_out);

    (void)in_sizes; (void)n_in; (void)out_size; (void)ws_size;
}

// Round 2
// 1270.444 us; speedup vs baseline: 4.8026x; 4.8026x over previous
//
#include <hip/hip_runtime.h>
#include <math.h>

constexpr int B    = 4;
constexpr int NPTS = 4096;
constexpr int CIN  = 9;
constexpr int C0   = 18;
constexpr int KNB  = 8;
constexpr int HID  = 128;
constexpr int QR   = 64;    // q rows per fmha block (16 per wave)
constexpr int KC   = 64;    // m per fmha tile
constexpr float EPSF = 1e-5f;

using f32x4  = __attribute__((ext_vector_type(4))) float;
using bf16x8 = __attribute__((ext_vector_type(8))) short;

// float -> bf16 bits, round-to-nearest-even (finite values)
__device__ inline unsigned short f2bf(float f) {
    unsigned int x = __float_as_uint(f);
    unsigned int r = (x + 0x7fffu + ((x >> 16) & 1u)) >> 16;
    return (unsigned short)r;
}
__device__ inline unsigned int pack2(float a, float b) {
    return (unsigned int)f2bf(a) | ((unsigned int)f2bf(b) << 16);
}

// ---------------- KNN + local diff features ----------------
__global__ __launch_bounds__(256) void knn_kernel(const float* __restrict__ x,
                                                  float* __restrict__ h0) {
    const int tid = threadIdx.x;
    const int gid = blockIdx.x * 256 + tid;
    const int b = gid >> 12;
    const int n = gid & (NPTS - 1);
    __shared__ float sx[256][3];
    const float* xb = x + (size_t)b * NPTS * CIN;
    const float qx = xb[n * CIN + 0];
    const float qy = xb[n * CIN + 1];
    const float qz = xb[n * CIN + 2];
    float bd[KNB];
    int   bi[KNB];
#pragma unroll
    for (int i = 0; i < KNB; ++i) { bd[i] = 3.0e38f; bi[i] = 0; }
    for (int t0 = 0; t0 < NPTS; t0 += 256) {
        __syncthreads();
        const int mload = t0 + tid;
        sx[tid][0] = xb[mload * CIN + 0];
        sx[tid][1] = xb[mload * CIN + 1];
        sx[tid][2] = xb[mload * CIN + 2];
        __syncthreads();
        for (int j = 0; j < 256; ++j) {
            const float dx = sx[j][0] - qx;
            const float dy = sx[j][1] - qy;
            const float dz = sx[j][2] - qz;
            const float d2 = dx * dx + dy * dy + dz * dz;
            const int m = t0 + j;
            if (d2 < bd[KNB - 1] && m != n) {
                bd[KNB - 1] = d2; bi[KNB - 1] = m;
#pragma unroll
                for (int p = KNB - 1; p > 0; --p) {
                    if (bd[p] < bd[p - 1]) {
                        float td = bd[p]; bd[p] = bd[p - 1]; bd[p - 1] = td;
                        int   ti = bi[p]; bi[p] = bi[p - 1]; bi[p - 1] = ti;
                    }
                }
            }
        }
    }
    float sums[CIN];
#pragma unroll
    for (int c = 0; c < CIN; ++c) sums[c] = 0.f;
    for (int k = 0; k < KNB; ++k) {
        const float* xp = xb + (size_t)bi[k] * CIN;
#pragma unroll
        for (int c = 0; c < CIN; ++c) sums[c] += xp[c];
    }
    const float inv = 1.0f / (float)KNB;
#pragma unroll
    for (int c = 0; c < CIN; ++c) {
        const float xv = xb[n * CIN + c];
        h0[((size_t)b * C0 + c) * NPTS + n]       = sums[c] * inv - xv;
        h0[((size_t)b * C0 + CIN + c) * NPTS + n] = xv;
    }
}

// ---------------- 1x1 conv: Y[b,o,n] = sum_c W[o,c] X[b,c,n] + bias[o] ----------------
// OUTM: 0 = f32 [o][n]; 1 = bf16 [n][o] (Q,K for MFMA); 2 = bf16 [o][n] (V for MFMA)
template <int OUTM, bool RELU, bool RES>
__global__ __launch_bounds__(256) void conv_kernel(const float* __restrict__ X,
                                                   const float* __restrict__ W,
                                                   const float* __restrict__ bias,
                                                   const float* __restrict__ res,
                                                   void* __restrict__ Yv,
                                                   int C, int O) {
    __shared__ float Ws[16 * 256];
    const int b  = blockIdx.z;
    const int o_base = blockIdx.y * 16;
    const int n  = blockIdx.x * 64 + (threadIdx.x & 63);
    const int og = threadIdx.x >> 6;
    const int rows = min(16, O - o_base);
    for (int i = threadIdx.x; i < rows * C; i += 256)
        Ws[i] = W[(size_t)o_base * C + i];
    __syncthreads();
    float acc[4] = {0.f, 0.f, 0.f, 0.f};
    const float* Xp = X + (size_t)b * C * NPTS + n;
    for (int c = 0; c < C; ++c) {
        const float xv = Xp[(size_t)c * NPTS];
#pragma unroll
        for (int i = 0; i < 4; ++i)
            acc[i] = fmaf(Ws[(og * 4 + i) * C + c], xv, acc[i]);
    }
    float v[4];
#pragma unroll
    for (int i = 0; i < 4; ++i) {
        const int o = o_base + og * 4 + i;
        v[i] = acc[i] + bias[min(o, O - 1)];
        if (RES)  v[i] += res[((size_t)b * O + o) * NPTS + n];
        if (RELU) v[i] = fmaxf(v[i], 0.f);
    }
    if (OUTM == 0) {
        float* Y = (float*)Yv;
#pragma unroll
        for (int i = 0; i < 4; ++i) {
            const int o = o_base + og * 4 + i;
            if (o < O) Y[((size_t)b * O + o) * NPTS + n] = v[i];
        }
    } else if (OUTM == 1) {
        unsigned short* Y = (unsigned short*)Yv;
        ushort4 pk;
        pk.x = f2bf(v[0]); pk.y = f2bf(v[1]); pk.z = f2bf(v[2]); pk.w = f2bf(v[3]);
        *(ushort4*)(Y + ((size_t)b * NPTS + n) * O + o_base + og * 4) = pk;
    } else {
        unsigned short* Y = (unsigned short*)Yv;
#pragma unroll
        for (int i = 0; i < 4; ++i) {
            const int o = o_base + og * 4 + i;
            Y[((size_t)b * O + o) * NPTS + n] = f2bf(v[i]);
        }
    }
}

// ---------------- BN statistics ----------------
__global__ __launch_bounds__(256) void bn_stats_kernel(const float* __restrict__ Y,
                                                       float* __restrict__ mean,
                                                       float* __restrict__ istd,
                                                       int O) {
    const int o = blockIdx.x;
    const int tid = threadIdx.x;
    __shared__ double rs[256];
    __shared__ double rs2[256];
    double s = 0.0, s2 = 0.0;
    for (int i = tid; i < B * NPTS; i += 256) {
        const int bb = i >> 12;
        const int nn = i & (NPTS - 1);
        const float v = Y[((size_t)bb * O + o) * NPTS + nn];
        s  += (double)v;
        s2 += (double)v * (double)v;
    }
    rs[tid] = s; rs2[tid] = s2;
    __syncthreads();
    for (int st = 128; st > 0; st >>= 1) {
        if (tid < st) { rs[tid] += rs[tid + st]; rs2[tid] += rs2[tid + st]; }
        __syncthreads();
    }
    if (tid == 0) {
        const double M = (double)(B * NPTS);
        const double m = rs[0] / M;
        const double var = rs2[0] / M - m * m;
        mean[o] = (float)m;
        istd[o] = (float)(1.0 / sqrt(var + (double)EPSF));
    }
}

// ---------------- BN apply + ReLU ----------------
__global__ __launch_bounds__(256) void bn_relu_kernel(float* __restrict__ Y,
                                                      const float* __restrict__ g,
                                                      const float* __restrict__ be,
                                                      const float* __restrict__ mean,
                                                      const float* __restrict__ istd,
                                                      int O) {
    const size_t total = (size_t)B * O * NPTS;
    for (size_t idx = (size_t)blockIdx.x * 256 + threadIdx.x; idx < total;
         idx += (size_t)gridDim.x * 256) {
        const int o = (int)((idx / NPTS) % O);
        float v = Y[idx];
        v = g[o] * (v - mean[o]) * istd[o] + be[o];
        Y[idx] = fmaxf(v, 0.f);
    }
}

// ---------------- MFMA flash attention (two-pass) ----------------
// Qg,Kg: bf16 [B][N][128] row-major; Vg: bf16 [B][128][N]; Og: f32 [B][128][N]
__global__ __launch_bounds__(256) void fmha_kernel(const unsigned short* __restrict__ Qg,
                                                   const unsigned short* __restrict__ Kg,
                                                   const unsigned short* __restrict__ Vg,
                                                   float* __restrict__ Og) {
    __shared__ __align__(16) char lds[40960];
    char* ldsK = lds;                 // [64 m][128 h] bf16, byte ^ ((m&7)<<4)
    char* ldsV = lds + 16384;         // [128 h][64 m] bf16, byte ^ ((h&7)<<4)
    const int tid = threadIdx.x;
    const int w = tid >> 6, l = tid & 63;
    char* ldsP = lds + 32768 + w * 2048;  // per-wave [16 q][64 m] bf16, byte ^ ((q&7)<<4)
    const int b  = blockIdx.y;
    const int q0 = blockIdx.x * QR;
    const int lg = l >> 4;
    const int lq = l & 15;

    // Q fragments (B-operand): lane holds Q[q=lq][k=lg*8+i] for 4 k-slices
    bf16x8 qf[4];
    {
        const unsigned short* qp = Qg + ((size_t)b * NPTS + q0 + w * 16 + lq) * HID + lg * 8;
#pragma unroll
        for (int ks = 0; ks < 4; ++ks)
            qf[ks] = *(const bf16x8*)(qp + ks * 32);
    }
    const unsigned short* Kb = Kg + (size_t)b * NPTS * HID;
    const unsigned short* Vb = Vg + (size_t)b * HID * NPTS;

    // ---- pass 1: row max ----
    float runmax = -3.0e38f;
    for (int n0 = 0; n0 < NPTS; n0 += KC) {
        __syncthreads();
#pragma unroll
        for (int i = 0; i < 4; ++i) {
            const int c = i * 256 + tid;
            const int m = c >> 4;
            const int lin = m * 256 + (c & 15) * 16;
            *(bf16x8*)(ldsK + (lin ^ ((m & 7) << 4))) =
                *(const bf16x8*)(Kb + (size_t)(n0 + m) * HID + (c & 15) * 8);
        }
        __syncthreads();
#pragma unroll
        for (int ms = 0; ms < 4; ++ms) {
            const int row = ms * 16 + lq;
            f32x4 s = {0.f, 0.f, 0.f, 0.f};
#pragma unroll
            for (int ks = 0; ks < 4; ++ks) {
                bf16x8 kf = *(const bf16x8*)(ldsK + ((row * 256 + ks * 64 + lg * 16) ^ ((row & 7) << 4)));
                s = __builtin_amdgcn_mfma_f32_16x16x32_bf16(kf, qf[ks], s, 0, 0, 0);
            }
#pragma unroll
            for (int r = 0; r < 4; ++r) runmax = fmaxf(runmax, s[r]);
        }
    }
    runmax = fmaxf(runmax, __shfl_xor(runmax, 16));
    runmax = fmaxf(runmax, __shfl_xor(runmax, 32));

    // ---- pass 2: exp-sum + PV ----
    float lsum = 0.f;
    f32x4 oacc[8];
#pragma unroll
    for (int hs = 0; hs < 8; ++hs) oacc[hs] = {0.f, 0.f, 0.f, 0.f};
    for (int n0 = 0; n0 < NPTS; n0 += KC) {
        __syncthreads();
#pragma unroll
        for (int i = 0; i < 4; ++i) {
            const int c = i * 256 + tid;
            const int m = c >> 4;
            const int lin = m * 256 + (c & 15) * 16;
            *(bf16x8*)(ldsK + (lin ^ ((m & 7) << 4))) =
                *(const bf16x8*)(Kb + (size_t)(n0 + m) * HID + (c & 15) * 8);
            const int h = c >> 3;
            const int linv = h * 128 + (c & 7) * 16;
            *(bf16x8*)(ldsV + (linv ^ ((h & 7) << 4))) =
                *(const bf16x8*)(Vb + (size_t)h * NPTS + n0 + (c & 7) * 8);
        }
        __syncthreads();
#pragma unroll
        for (int ms = 0; ms < 4; ++ms) {
            const int row = ms * 16 + lq;
            f32x4 s = {0.f, 0.f, 0.f, 0.f};
#pragma unroll
            for (int ks = 0; ks < 4; ++ks) {
                bf16x8 kf = *(const bf16x8*)(ldsK + ((row * 256 + ks * 64 + lg * 16) ^ ((row & 7) << 4)));
                s = __builtin_amdgcn_mfma_f32_16x16x32_bf16(kf, qf[ks], s, 0, 0, 0);
            }
            const float p0 = __expf(s[0] - runmax);
            const float p1 = __expf(s[1] - runmax);
            const float p2 = __expf(s[2] - runmax);
            const float p3 = __expf(s[3] - runmax);
            lsum += (p0 + p1) + (p2 + p3);
            const int lin = lq * 128 + ms * 32 + lg * 8;
            const int ad  = lin ^ ((lq & 7) << 4);
            *(unsigned int*)(ldsP + ad)     = pack2(p0, p1);
            *(unsigned int*)(ldsP + ad + 4) = pack2(p2, p3);
        }
#pragma unroll
        for (int msl = 0; msl < 2; ++msl) {
            bf16x8 pf = *(const bf16x8*)(ldsP + ((lq * 128 + msl * 64 + lg * 16) ^ ((lq & 7) << 4)));
#pragma unroll
            for (int hs = 0; hs < 8; ++hs) {
                const int hrow = hs * 16 + lq;
                bf16x8 vf = *(const bf16x8*)(ldsV + ((hrow * 128 + msl * 64 + lg * 16) ^ ((hrow & 7) << 4)));
                oacc[hs] = __builtin_amdgcn_mfma_f32_16x16x32_bf16(pf, vf, oacc[hs], 0, 0, 0);
            }
        }
    }
    lsum += __shfl_xor(lsum, 16);
    lsum += __shfl_xor(lsum, 32);
    const float inv = 1.0f / lsum;
    float invq[4];
#pragma unroll
    for (int r = 0; r < 4; ++r) invq[r] = __shfl(inv, lg * 4 + r);
    float* Ob = Og + (size_t)b * HID * NPTS + q0 + w * 16;
#pragma unroll
    for (int hs = 0; hs < 8; ++hs) {
#pragma unroll
        for (int r = 0; r < 4; ++r)
            Ob[(size_t)(hs * 16 + lq) * NPTS + lg * 4 + r] = oacc[hs][r] * invq[r];
    }
}

// ---------------- softmax over N of pooling scores ----------------
__global__ __launch_bounds__(256) void softmax_w_kernel(float* __restrict__ s) {
    const int b = blockIdx.x;
    const int tid = threadIdx.x;
    __shared__ float red[256];
    float lm = -3.0e38f;
    for (int n = tid; n < NPTS; n += 256) lm = fmaxf(lm, s[b * NPTS + n]);
    red[tid] = lm;
    __syncthreads();
    for (int st = 128; st > 0; st >>= 1) {
        if (tid < st) red[tid] = fmaxf(red[tid], red[tid + st]);
        __syncthreads();
    }
    const float mx = red[0];
    __syncthreads();
    float ls = 0.f;
    for (int n = tid; n < NPTS; n += 256) {
        const float p = __expf(s[b * NPTS + n] - mx);
        s[b * NPTS + n] = p;
        ls += p;
    }
    red[tid] = ls;
    __syncthreads();
    for (int st = 128; st > 0; st >>= 1) {
        if (tid < st) red[tid] += red[tid + st];
        __syncthreads();
    }
    const float inv = 1.f / red[0];
    __syncthreads();
    for (int n = tid; n < NPTS; n += 256) s[b * NPTS + n] *= inv;
}

// ---------------- weighted pooling ----------------
__global__ __launch_bounds__(256) void pool_kernel(const float* __restrict__ h,
                                                   const float* __restrict__ w,
                                                   float* __restrict__ pooled) {
    const int c = blockIdx.x, b = blockIdx.y, tid = threadIdx.x;
    __shared__ float red[256];
    const float* hp = h + ((size_t)b * 256 + c) * NPTS;
    const float* wp = w + (size_t)b * NPTS;
    float acc = 0.f;
    for (int n = tid; n < NPTS; n += 256) acc = fmaf(hp[n], wp[n], acc);
    red[tid] = acc;
    __syncthreads();
    for (int st = 128; st > 0; st >>= 1) {
        if (tid < st) red[tid] += red[tid + st];
        __syncthreads();
    }
    if (tid == 0) pooled[b * 256 + c] = red[0];
}

// ---------------- final FC + ReLU ----------------
__global__ __launch_bounds__(256) void fc_kernel(const float* __restrict__ pooled,
                                                 const float* __restrict__ fcw,
                                                 const float* __restrict__ fcb,
                                                 float* __restrict__ out) {
    const int b = blockIdx.x, j = threadIdx.x;
    __shared__ float ps[256];
    ps[j] = pooled[b * 256 + j];
    __syncthreads();
    float acc = fcb[j];
    for (int c = 0; c < 256; ++c) acc = fmaf(ps[c], fcw[j * 256 + c], acc);
    out[b * 256 + j] = fmaxf(acc, 0.f);
}

extern "C" void kernel_launch(void* const* d_in, const int* in_sizes, int n_in,
                              void* d_out, int out_size, void* d_ws, size_t ws_size,
                              hipStream_t stream) {
    const float* x   = (const float*)d_in[0];
    const float* w1  = (const float*)d_in[1];
    const float* b1  = (const float*)d_in[2];
    const float* g1  = (const float*)d_in[3];
    const float* be1 = (const float*)d_in[4];
    const float* w2  = (const float*)d_in[5];
    const float* b2  = (const float*)d_in[6];
    const float* g2  = (const float*)d_in[7];
    const float* be2 = (const float*)d_in[8];
    const float* w3  = (const float*)d_in[9];
    const float* b3  = (const float*)d_in[10];
    const float* g3  = (const float*)d_in[11];
    const float* be3 = (const float*)d_in[12];
    const float* qw  = (const float*)d_in[13];
    const float* qb  = (const float*)d_in[14];
    const float* kw  = (const float*)d_in[15];
    const float* kb  = (const float*)d_in[16];
    const float* vw  = (const float*)d_in[17];
    const float* vb  = (const float*)d_in[18];
    const float* fw  = (const float*)d_in[19];
    const float* fb  = (const float*)d_in[20];
    const float* aw1 = (const float*)d_in[21];
    const float* ab1 = (const float*)d_in[22];
    const float* aw2 = (const float*)d_in[23];
    const float* ab2 = (const float*)d_in[24];
    const float* fcw = (const float*)d_in[25];
    const float* fcb = (const float*)d_in[26];

    float* ws = (float*)d_ws;
    float* h0 = ws;                     // 4*18*4096
    float* h1 = h0 + 294912;            // 4*64*4096
    float* h2 = h1 + 1048576;           // 4*128*4096
    float* h3 = h2 + 2097152;           // 4*256*4096
    float* Q  = h3 + 4194304;           // bf16 [B][N][128] (slot sized for f32)
    float* K  = Q  + 2097152;
    float* V  = K  + 2097152;
    float* Oa = V  + 2097152;           // f32 [B][128][N]
    float* h4 = Oa + 2097152;           // 4*256*4096
    float* a  = h4 + 4194304;
    float* s  = a  + 1048576;
    float* pooled = s + 16384;
    float* mean   = pooled + 1024;
    float* istd   = mean + 256;

    unsigned short* Qb = (unsigned short*)Q;
    unsigned short* Kb = (unsigned short*)K;
    unsigned short* Vb = (unsigned short*)V;

    knn_kernel<<<dim3(B * NPTS / 256), 256, 0, stream>>>(x, h0);

    // layer 1: 18 -> 64
    conv_kernel<0, false, false><<<dim3(NPTS / 64, 4, B), 256, 0, stream>>>(h0, w1, b1, nullptr, h1, C0, 64);
    bn_stats_kernel<<<64, 256, 0, stream>>>(h1, mean, istd, 64);
    bn_relu_kernel<<<2048, 256, 0, stream>>>(h1, g1, be1, mean, istd, 64);
    // layer 2: 64 -> 128
    conv_kernel<0, false, false><<<dim3(NPTS / 64, 8, B), 256, 0, stream>>>(h1, w2, b2, nullptr, h2, 64, 128);
    bn_stats_kernel<<<128, 256, 0, stream>>>(h2, mean, istd, 128);
    bn_relu_kernel<<<2048, 256, 0, stream>>>(h2, g2, be2, mean, istd, 128);
    // layer 3: 128 -> 256
    conv_kernel<0, false, false><<<dim3(NPTS / 64, 16, B), 256, 0, stream>>>(h2, w3, b3, nullptr, h3, 128, 256);
    bn_stats_kernel<<<256, 256, 0, stream>>>(h3, mean, istd, 256);
    bn_relu_kernel<<<2048, 256, 0, stream>>>(h3, g3, be3, mean, istd, 256);

    // Q, K projections -> bf16 [n][h]; V -> bf16 [h][n]
    conv_kernel<1, false, false><<<dim3(NPTS / 64, 8, B), 256, 0, stream>>>(h3, qw, qb, nullptr, Qb, 256, 128);
    conv_kernel<1, false, false><<<dim3(NPTS / 64, 8, B), 256, 0, stream>>>(h3, kw, kb, nullptr, Kb, 256, 128);
    conv_kernel<2, false, false><<<dim3(NPTS / 64, 8, B), 256, 0, stream>>>(h3, vw, vb, nullptr, Vb, 256, 128);

    fmha_kernel<<<dim3(NPTS / QR, B), 256, 0, stream>>>(Qb, Kb, Vb, Oa);

    // fuse-out conv + residual: 128 -> 256, + h3
    conv_kernel<0, false, true><<<dim3(NPTS / 64, 16, B), 256, 0, stream>>>(Oa, fw, fb, h3, h4, 128, 256);
    // attention-pool MLP
    conv_kernel<0, true, false><<<dim3(NPTS / 64, 4, B), 256, 0, stream>>>(h4, aw1, ab1, nullptr, a, 256, 64);
    conv_kernel<0, false, false><<<dim3(NPTS / 64, 1, B), 256, 0, stream>>>(a, aw2, ab2, nullptr, s, 64, 1);

    softmax_w_kernel<<<B, 256, 0, stream>>>(s);
    pool_kernel<<<dim3(256, B), 256, 0, stream>>>(h4, s, pooled);
    fc_kernel<<<B, 256, 0, stream>>>(pooled, fcw, fcb, (float*)d_out);

    (void)in_sizes; (void)n_in; (void)out_size; (void)ws_size;
}

// Round 3
// 816.680 us; speedup vs baseline: 7.4711x; 1.5556x over previous
//
#include <hip/hip_runtime.h>
#include <math.h>

constexpr int B    = 4;
constexpr int NPTS = 4096;
constexpr int CIN  = 9;
constexpr int C0   = 18;
constexpr int KNB  = 8;
constexpr int HID  = 128;
constexpr int QR   = 64;    // q rows per fmha block (16 per wave)
constexpr int KC   = 64;    // m per fmha tile
constexpr float EPSF = 1e-5f;

using f32x4  = __attribute__((ext_vector_type(4))) float;
using bf16x8 = __attribute__((ext_vector_type(8))) short;

// float -> bf16 bits, round-to-nearest-even (finite values)
__device__ inline unsigned short f2bf(float f) {
    unsigned int x = __float_as_uint(f);
    unsigned int r = (x + 0x7fffu + ((x >> 16) & 1u)) >> 16;
    return (unsigned short)r;
}
__device__ inline unsigned int pack2(float a, float b) {
    return (unsigned int)f2bf(a) | ((unsigned int)f2bf(b) << 16);
}

// ---------------- pack xyz + |xyz|^2 into float4 ----------------
__global__ __launch_bounds__(256) void pack_kernel(const float* __restrict__ x,
                                                   float4* __restrict__ xyzw) {
    const int gid = blockIdx.x * 256 + threadIdx.x;   // B*NPTS
    const float* xp = x + (size_t)gid * CIN;
    const float a = xp[0], b = xp[1], c = xp[2];
    xyzw[gid] = make_float4(a, b, c, a * a + b * b + c * c);
}

// ---------------- KNN (split-scan) + local diff features ----------------
// block: 256 threads = 32 points x 8 chunks. grid: B * NPTS/32.
// LDS: whole batch xyzw staged as [j][chunk] float4 (64 KB), then aliased for merge.
__global__ __launch_bounds__(256) void knn2_kernel(const float* __restrict__ x,
                                                   const float4* __restrict__ xyzw,
                                                   float* __restrict__ h0) {
    __shared__ __align__(16) char ldsbuf[65536];
    float4* sxy = (float4*)ldsbuf;                 // [512 j][8 c]
    const int tid = threadIdx.x;
    const int b  = blockIdx.x >> 7;
    const int p0 = (blockIdx.x & 127) << 5;        // 32 points per block
    const int p  = tid >> 3;                       // point within block
    const int c  = tid & 7;                        // chunk
    const float4* xb4 = xyzw + (size_t)b * NPTS;

    // stage whole batch xyzw -> LDS (chunk-interleaved)
#pragma unroll
    for (int i = 0; i < 16; ++i) {
        const int m = tid + i * 256;
        sxy[(m & 511) * 8 + (m >> 9)] = xb4[m];
    }
    __syncthreads();

    const int n = p0 + p;                          // this thread's point
    const float4 q4 = sxy[(n & 511) * 8 + (n >> 9)];
    const float qx = q4.x, qy = q4.y, qz = q4.z, sqn = q4.w;

    // scan 512 candidates: chunk c covers m in [c*512, c*512+512)
    float bd[KNB];
    int   bi[KNB];
#pragma unroll
    for (int i = 0; i < KNB; ++i) { bd[i] = 3.0e38f; bi[i] = 0; }
    const float4* rowp = sxy + c;
#pragma unroll 2
    for (int j = 0; j < 512; ++j) {
        const float4 f4 = rowp[j * 8];
        const float t  = fmaf(qx, f4.x, fmaf(qy, f4.y, qz * f4.z));
        const float d2 = fmaf(-2.0f, t, sqn + f4.w);
        const int m = c * 512 + j;
        if (d2 < bd[KNB - 1] && m != n) {
            bd[KNB - 1] = d2; bi[KNB - 1] = m;
#pragma unroll
            for (int s = KNB - 1; s > 0; --s) {
                if (bd[s] < bd[s - 1]) {
                    float td = bd[s]; bd[s] = bd[s - 1]; bd[s - 1] = td;
                    int   ti = bi[s]; bi[s] = bi[s - 1]; bi[s - 1] = ti;
                }
            }
        }
    }
    __syncthreads();                               // done reading sxy

    // merge: [32 p][8 c * 8 rank]
    float* mbD = (float*)ldsbuf;                   // 8 KB
    int*   mbI = (int*)(ldsbuf + 8192);            // 8 KB
    int*   idxL = (int*)(ldsbuf + 16384);          // 32*8 ints
#pragma unroll
    for (int k = 0; k < KNB; ++k) {
        mbD[p * 64 + c * 8 + k] = bd[k];
        mbI[p * 64 + c * 8 + k] = bi[k];
    }
    __syncthreads();
    if (tid < 32) {
        float fd[KNB]; int fi[KNB];
#pragma unroll
        for (int i = 0; i < KNB; ++i) { fd[i] = 3.0e38f; fi[i] = 0; }
        for (int e = 0; e < 64; ++e) {
            const float d = mbD[tid * 64 + e];
            if (d < fd[KNB - 1]) {
                fd[KNB - 1] = d; fi[KNB - 1] = mbI[tid * 64 + e];
#pragma unroll
                for (int s = KNB - 1; s > 0; --s) {
                    if (fd[s] < fd[s - 1]) {
                        float td = fd[s]; fd[s] = fd[s - 1]; fd[s - 1] = td;
                        int   ti = fi[s]; fi[s] = fi[s - 1]; fi[s - 1] = ti;
                    }
                }
            }
        }
#pragma unroll
        for (int k = 0; k < KNB; ++k) idxL[tid * 8 + k] = fi[k];
    }
    __syncthreads();

    // gather: thread (p, k=c) loads neighbor's 9 channels, butterfly-sum over 8 lanes
    const int nb = idxL[p * 8 + c];
    const float* xb = x + (size_t)b * NPTS * CIN;
    float nv[CIN];
    const float* nbp = xb + (size_t)nb * CIN;
#pragma unroll
    for (int ch = 0; ch < CIN; ++ch) nv[ch] = nbp[ch];
#pragma unroll
    for (int d = 1; d < 8; d <<= 1) {
#pragma unroll
        for (int ch = 0; ch < CIN; ++ch) nv[ch] += __shfl_xor(nv[ch], d);
    }
    // lane c writes channel c; lane 0 also channel 8
    {
        const int ch = c;
        const float xv = xb[(size_t)n * CIN + ch];
        h0[((size_t)b * C0 + ch) * NPTS + n]       = nv[ch] * 0.125f - xv;
        h0[((size_t)b * C0 + CIN + ch) * NPTS + n] = xv;
    }
    if (c == 0) {
        const int ch = 8;
        const float xv = xb[(size_t)n * CIN + ch];
        h0[((size_t)b * C0 + ch) * NPTS + n]       = nv[ch] * 0.125f - xv;
        h0[((size_t)b * C0 + CIN + ch) * NPTS + n] = xv;
    }
}

// ---------------- 1x1 conv: Y[b,o,n] = sum_c W[o,c] X[b,c,n] + bias[o] ----------------
// OUTM: 0 = f32 [o][n]; 1 = bf16 [n][o] (Q,K for MFMA); 2 = bf16 [o][n] (V for MFMA)
template <int OUTM, bool RELU, bool RES>
__global__ __launch_bounds__(256) void conv_kernel(const float* __restrict__ X,
                                                   const float* __restrict__ W,
                                                   const float* __restrict__ bias,
                                                   const float* __restrict__ res,
                                                   void* __restrict__ Yv,
                                                   int C, int O) {
    __shared__ float Ws[16 * 256];
    const int b  = blockIdx.z;
    const int o_base = blockIdx.y * 16;
    const int n  = blockIdx.x * 64 + (threadIdx.x & 63);
    const int og = threadIdx.x >> 6;
    const int rows = min(16, O - o_base);
    for (int i = threadIdx.x; i < rows * C; i += 256)
        Ws[i] = W[(size_t)o_base * C + i];
    __syncthreads();
    float acc[4] = {0.f, 0.f, 0.f, 0.f};
    const float* Xp = X + (size_t)b * C * NPTS + n;
    for (int c = 0; c < C; ++c) {
        const float xv = Xp[(size_t)c * NPTS];
#pragma unroll
        for (int i = 0; i < 4; ++i)
            acc[i] = fmaf(Ws[(og * 4 + i) * C + c], xv, acc[i]);
    }
    float v[4];
#pragma unroll
    for (int i = 0; i < 4; ++i) {
        const int o = o_base + og * 4 + i;
        v[i] = acc[i] + bias[min(o, O - 1)];
        if (RES)  v[i] += res[((size_t)b * O + o) * NPTS + n];
        if (RELU) v[i] = fmaxf(v[i], 0.f);
    }
    if (OUTM == 0) {
        float* Y = (float*)Yv;
#pragma unroll
        for (int i = 0; i < 4; ++i) {
            const int o = o_base + og * 4 + i;
            if (o < O) Y[((size_t)b * O + o) * NPTS + n] = v[i];
        }
    } else if (OUTM == 1) {
        unsigned short* Y = (unsigned short*)Yv;
        ushort4 pk;
        pk.x = f2bf(v[0]); pk.y = f2bf(v[1]); pk.z = f2bf(v[2]); pk.w = f2bf(v[3]);
        *(ushort4*)(Y + ((size_t)b * NPTS + n) * O + o_base + og * 4) = pk;
    } else {
        unsigned short* Y = (unsigned short*)Yv;
#pragma unroll
        for (int i = 0; i < 4; ++i) {
            const int o = o_base + og * 4 + i;
            Y[((size_t)b * O + o) * NPTS + n] = f2bf(v[i]);
        }
    }
}

// ---------------- BN statistics ----------------
__global__ __launch_bounds__(256) void bn_stats_kernel(const float* __restrict__ Y,
                                                       float* __restrict__ mean,
                                                       float* __restrict__ istd,
                                                       int O) {
    const int o = blockIdx.x;
    const int tid = threadIdx.x;
    __shared__ double rs[256];
    __shared__ double rs2[256];
    double s = 0.0, s2 = 0.0;
    for (int i = tid; i < B * NPTS; i += 256) {
        const int bb = i >> 12;
        const int nn = i & (NPTS - 1);
        const float v = Y[((size_t)bb * O + o) * NPTS + nn];
        s  += (double)v;
        s2 += (double)v * (double)v;
    }
    rs[tid] = s; rs2[tid] = s2;
    __syncthreads();
    for (int st = 128; st > 0; st >>= 1) {
        if (tid < st) { rs[tid] += rs[tid + st]; rs2[tid] += rs2[tid + st]; }
        __syncthreads();
    }
    if (tid == 0) {
        const double M = (double)(B * NPTS);
        const double m = rs[0] / M;
        const double var = rs2[0] / M - m * m;
        mean[o] = (float)m;
        istd[o] = (float)(1.0 / sqrt(var + (double)EPSF));
    }
}

// ---------------- BN apply + ReLU ----------------
__global__ __launch_bounds__(256) void bn_relu_kernel(float* __restrict__ Y,
                                                      const float* __restrict__ g,
                                                      const float* __restrict__ be,
                                                      const float* __restrict__ mean,
                                                      const float* __restrict__ istd,
                                                      int O) {
    const size_t total = (size_t)B * O * NPTS;
    for (size_t idx = (size_t)blockIdx.x * 256 + threadIdx.x; idx < total;
         idx += (size_t)gridDim.x * 256) {
        const int o = (int)((idx / NPTS) % O);
        float v = Y[idx];
        v = g[o] * (v - mean[o]) * istd[o] + be[o];
        Y[idx] = fmaxf(v, 0.f);
    }
}

// ---------------- MFMA flash attention (two-pass) ----------------
__global__ __launch_bounds__(256) void fmha_kernel(const unsigned short* __restrict__ Qg,
                                                   const unsigned short* __restrict__ Kg,
                                                   const unsigned short* __restrict__ Vg,
                                                   float* __restrict__ Og) {
    __shared__ __align__(16) char lds[40960];
    char* ldsK = lds;                 // [64 m][128 h] bf16, byte ^ ((m&7)<<4)
    char* ldsV = lds + 16384;         // [128 h][64 m] bf16, byte ^ ((h&7)<<4)
    const int tid = threadIdx.x;
    const int w = tid >> 6, l = tid & 63;
    char* ldsP = lds + 32768 + w * 2048;  // per-wave [16 q][64 m] bf16, byte ^ ((q&7)<<4)
    const int b  = blockIdx.y;
    const int q0 = blockIdx.x * QR;
    const int lg = l >> 4;
    const int lq = l & 15;

    bf16x8 qf[4];
    {
        const unsigned short* qp = Qg + ((size_t)b * NPTS + q0 + w * 16 + lq) * HID + lg * 8;
#pragma unroll
        for (int ks = 0; ks < 4; ++ks)
            qf[ks] = *(const bf16x8*)(qp + ks * 32);
    }
    const unsigned short* Kb = Kg + (size_t)b * NPTS * HID;
    const unsigned short* Vb = Vg + (size_t)b * HID * NPTS;

    // ---- pass 1: row max ----
    float runmax = -3.0e38f;
    for (int n0 = 0; n0 < NPTS; n0 += KC) {
        __syncthreads();
#pragma unroll
        for (int i = 0; i < 4; ++i) {
            const int c = i * 256 + tid;
            const int m = c >> 4;
            const int lin = m * 256 + (c & 15) * 16;
            *(bf16x8*)(ldsK + (lin ^ ((m & 7) << 4))) =
                *(const bf16x8*)(Kb + (size_t)(n0 + m) * HID + (c & 15) * 8);
        }
        __syncthreads();
#pragma unroll
        for (int ms = 0; ms < 4; ++ms) {
            const int row = ms * 16 + lq;
            f32x4 s = {0.f, 0.f, 0.f, 0.f};
#pragma unroll
            for (int ks = 0; ks < 4; ++ks) {
                bf16x8 kf = *(const bf16x8*)(ldsK + ((row * 256 + ks * 64 + lg * 16) ^ ((row & 7) << 4)));
                s = __builtin_amdgcn_mfma_f32_16x16x32_bf16(kf, qf[ks], s, 0, 0, 0);
            }
#pragma unroll
            for (int r = 0; r < 4; ++r) runmax = fmaxf(runmax, s[r]);
        }
    }
    runmax = fmaxf(runmax, __shfl_xor(runmax, 16));
    runmax = fmaxf(runmax, __shfl_xor(runmax, 32));

    // ---- pass 2: exp-sum + PV ----
    float lsum = 0.f;
    f32x4 oacc[8];
#pragma unroll
    for (int hs = 0; hs < 8; ++hs) oacc[hs] = {0.f, 0.f, 0.f, 0.f};
    for (int n0 = 0; n0 < NPTS; n0 += KC) {
        __syncthreads();
#pragma unroll
        for (int i = 0; i < 4; ++i) {
            const int c = i * 256 + tid;
            const int m = c >> 4;
            const int lin = m * 256 + (c & 15) * 16;
            *(bf16x8*)(ldsK + (lin ^ ((m & 7) << 4))) =
                *(const bf16x8*)(Kb + (size_t)(n0 + m) * HID + (c & 15) * 8);
            const int h = c >> 3;
            const int linv = h * 128 + (c & 7) * 16;
            *(bf16x8*)(ldsV + (linv ^ ((h & 7) << 4))) =
                *(const bf16x8*)(Vb + (size_t)h * NPTS + n0 + (c & 7) * 8);
        }
        __syncthreads();
#pragma unroll
        for (int ms = 0; ms < 4; ++ms) {
            const int row = ms * 16 + lq;
            f32x4 s = {0.f, 0.f, 0.f, 0.f};
#pragma unroll
            for (int ks = 0; ks < 4; ++ks) {
                bf16x8 kf = *(const bf16x8*)(ldsK + ((row * 256 + ks * 64 + lg * 16) ^ ((row & 7) << 4)));
                s = __builtin_amdgcn_mfma_f32_16x16x32_bf16(kf, qf[ks], s, 0, 0, 0);
            }
            const float p0 = __expf(s[0] - runmax);
            const float p1 = __expf(s[1] - runmax);
            const float p2 = __expf(s[2] - runmax);
            const float p3 = __expf(s[3] - runmax);
            lsum += (p0 + p1) + (p2 + p3);
            const int lin = lq * 128 + ms * 32 + lg * 8;
            const int ad  = lin ^ ((lq & 7) << 4);
            *(unsigned int*)(ldsP + ad)     = pack2(p0, p1);
            *(unsigned int*)(ldsP + ad + 4) = pack2(p2, p3);
        }
#pragma unroll
        for (int msl = 0; msl < 2; ++msl) {
            bf16x8 pf = *(const bf16x8*)(ldsP + ((lq * 128 + msl * 64 + lg * 16) ^ ((lq & 7) << 4)));
#pragma unroll
            for (int hs = 0; hs < 8; ++hs) {
                const int hrow = hs * 16 + lq;
                bf16x8 vf = *(const bf16x8*)(ldsV + ((hrow * 128 + msl * 64 + lg * 16) ^ ((hrow & 7) << 4)));
                oacc[hs] = __builtin_amdgcn_mfma_f32_16x16x32_bf16(pf, vf, oacc[hs], 0, 0, 0);
            }
        }
    }
    lsum += __shfl_xor(lsum, 16);
    lsum += __shfl_xor(lsum, 32);
    const float inv = 1.0f / lsum;
    float invq[4];
#pragma unroll
    for (int r = 0; r < 4; ++r) invq[r] = __shfl(inv, lg * 4 + r);
    float* Ob = Og + (size_t)b * HID * NPTS + q0 + w * 16;
#pragma unroll
    for (int hs = 0; hs < 8; ++hs) {
#pragma unroll
        for (int r = 0; r < 4; ++r)
            Ob[(size_t)(hs * 16 + lq) * NPTS + lg * 4 + r] = oacc[hs][r] * invq[r];
    }
}

// ---------------- softmax over N of pooling scores ----------------
__global__ __launch_bounds__(256) void softmax_w_kernel(float* __restrict__ s) {
    const int b = blockIdx.x;
    const int tid = threadIdx.x;
    __shared__ float red[256];
    float lm = -3.0e38f;
    for (int n = tid; n < NPTS; n += 256) lm = fmaxf(lm, s[b * NPTS + n]);
    red[tid] = lm;
    __syncthreads();
    for (int st = 128; st > 0; st >>= 1) {
        if (tid < st) red[tid] = fmaxf(red[tid], red[tid + st]);
        __syncthreads();
    }
    const float mx = red[0];
    __syncthreads();
    float ls = 0.f;
    for (int n = tid; n < NPTS; n += 256) {
        const float p = __expf(s[b * NPTS + n] - mx);
        s[b * NPTS + n] = p;
        ls += p;
    }
    red[tid] = ls;
    __syncthreads();
    for (int st = 128; st > 0; st >>= 1) {
        if (tid < st) red[tid] += red[tid + st];
        __syncthreads();
    }
    const float inv = 1.f / red[0];
    __syncthreads();
    for (int n = tid; n < NPTS; n += 256) s[b * NPTS + n] *= inv;
}

// ---------------- weighted pooling ----------------
__global__ __launch_bounds__(256) void pool_kernel(const float* __restrict__ h,
                                                   const float* __restrict__ w,
                                                   float* __restrict__ pooled) {
    const int c = blockIdx.x, b = blockIdx.y, tid = threadIdx.x;
    __shared__ float red[256];
    const float* hp = h + ((size_t)b * 256 + c) * NPTS;
    const float* wp = w + (size_t)b * NPTS;
    float acc = 0.f;
    for (int n = tid; n < NPTS; n += 256) acc = fmaf(hp[n], wp[n], acc);
    red[tid] = acc;
    __syncthreads();
    for (int st = 128; st > 0; st >>= 1) {
        if (tid < st) red[tid] += red[tid + st];
        __syncthreads();
    }
    if (tid == 0) pooled[b * 256 + c] = red[0];
}

// ---------------- final FC + ReLU ----------------
__global__ __launch_bounds__(256) void fc_kernel(const float* __restrict__ pooled,
                                                 const float* __restrict__ fcw,
                                                 const float* __restrict__ fcb,
                                                 float* __restrict__ out) {
    const int b = blockIdx.x, j = threadIdx.x;
    __shared__ float ps[256];
    ps[j] = pooled[b * 256 + j];
    __syncthreads();
    float acc = fcb[j];
    for (int c = 0; c < 256; ++c) acc = fmaf(ps[c], fcw[j * 256 + c], acc);
    out[b * 256 + j] = fmaxf(acc, 0.f);
}

extern "C" void kernel_launch(void* const* d_in, const int* in_sizes, int n_in,
                              void* d_out, int out_size, void* d_ws, size_t ws_size,
                              hipStream_t stream) {
    const float* x   = (const float*)d_in[0];
    const float* w1  = (const float*)d_in[1];
    const float* b1  = (const float*)d_in[2];
    const float* g1  = (const float*)d_in[3];
    const float* be1 = (const float*)d_in[4];
    const float* w2  = (const float*)d_in[5];
    const float* b2  = (const float*)d_in[6];
    const float* g2  = (const float*)d_in[7];
    const float* be2 = (const float*)d_in[8];
    const float* w3  = (const float*)d_in[9];
    const float* b3  = (const float*)d_in[10];
    const float* g3  = (const float*)d_in[11];
    const float* be3 = (const float*)d_in[12];
    const float* qw  = (const float*)d_in[13];
    const float* qb  = (const float*)d_in[14];
    const float* kw  = (const float*)d_in[15];
    const float* kb  = (const float*)d_in[16];
    const float* vw  = (const float*)d_in[17];
    const float* vb  = (const float*)d_in[18];
    const float* fw  = (const float*)d_in[19];
    const float* fb  = (const float*)d_in[20];
    const float* aw1 = (const float*)d_in[21];
    const float* ab1 = (const float*)d_in[22];
    const float* aw2 = (const float*)d_in[23];
    const float* ab2 = (const float*)d_in[24];
    const float* fcw = (const float*)d_in[25];
    const float* fcb = (const float*)d_in[26];

    float* ws = (float*)d_ws;
    float* h0 = ws;                     // 4*18*4096
    float* h1 = h0 + 294912;            // 4*64*4096
    float* h2 = h1 + 1048576;           // 4*128*4096
    float* h3 = h2 + 2097152;           // 4*256*4096
    float* Q  = h3 + 4194304;           // bf16 [B][N][128]
    float* K  = Q  + 2097152;
    float* V  = K  + 2097152;
    float* Oa = V  + 2097152;           // f32 [B][128][N]
    float* h4 = Oa + 2097152;           // 4*256*4096
    float* a  = h4 + 4194304;
    float* s  = a  + 1048576;
    float* pooled = s + 16384;
    float* mean   = pooled + 1024;
    float* istd   = mean + 256;
    float4* xyzw  = (float4*)(istd + 256);   // B*NPTS float4

    unsigned short* Qb = (unsigned short*)Q;
    unsigned short* Kb = (unsigned short*)K;
    unsigned short* Vb = (unsigned short*)V;

    pack_kernel<<<dim3(B * NPTS / 256), 256, 0, stream>>>(x, xyzw);
    knn2_kernel<<<dim3(B * NPTS / 32), 256, 0, stream>>>(x, xyzw, h0);

    // layer 1: 18 -> 64
    conv_kernel<0, false, false><<<dim3(NPTS / 64, 4, B), 256, 0, stream>>>(h0, w1, b1, nullptr, h1, C0, 64);
    bn_stats_kernel<<<64, 256, 0, stream>>>(h1, mean, istd, 64);
    bn_relu_kernel<<<2048, 256, 0, stream>>>(h1, g1, be1, mean, istd, 64);
    // layer 2: 64 -> 128
    conv_kernel<0, false, false><<<dim3(NPTS / 64, 8, B), 256, 0, stream>>>(h1, w2, b2, nullptr, h2, 64, 128);
    bn_stats_kernel<<<128, 256, 0, stream>>>(h2, mean, istd, 128);
    bn_relu_kernel<<<2048, 256, 0, stream>>>(h2, g2, be2, mean, istd, 128);
    // layer 3: 128 -> 256
    conv_kernel<0, false, false><<<dim3(NPTS / 64, 16, B), 256, 0, stream>>>(h2, w3, b3, nullptr, h3, 128, 256);
    bn_stats_kernel<<<256, 256, 0, stream>>>(h3, mean, istd, 256);
    bn_relu_kernel<<<2048, 256, 0, stream>>>(h3, g3, be3, mean, istd, 256);

    // Q, K projections -> bf16 [n][h]; V -> bf16 [h][n]
    conv_kernel<1, false, false><<<dim3(NPTS / 64, 8, B), 256, 0, stream>>>(h3, qw, qb, nullptr, Qb, 256, 128);
    conv_kernel<1, false, false><<<dim3(NPTS / 64, 8, B), 256, 0, stream>>>(h3, kw, kb, nullptr, Kb, 256, 128);
    conv_kernel<2, false, false><<<dim3(NPTS / 64, 8, B), 256, 0, stream>>>(h3, vw, vb, nullptr, Vb, 256, 128);

    fmha_kernel<<<dim3(NPTS / QR, B), 256, 0, stream>>>(Qb, Kb, Vb, Oa);

    // fuse-out conv + residual: 128 -> 256, + h3
    conv_kernel<0, false, true><<<dim3(NPTS / 64, 16, B), 256, 0, stream>>>(Oa, fw, fb, h3, h4, 128, 256);
    // attention-pool MLP
    conv_kernel<0, true, false><<<dim3(NPTS / 64, 4, B), 256, 0, stream>>>(h4, aw1, ab1, nullptr, a, 256, 64);
    conv_kernel<0, false, false><<<dim3(NPTS / 64, 1, B), 256, 0, stream>>>(a, aw2, ab2, nullptr, s, 64, 1);

    softmax_w_kernel<<<B, 256, 0, stream>>>(s);
    pool_kernel<<<dim3(256, B), 256, 0, stream>>>(h4, s, pooled);
    fc_kernel<<<B, 256, 0, stream>>>(pooled, fcw, fcb, (float*)d_out);

    (void)in_sizes; (void)n_in; (void)out_size; (void)ws_size;
}

// Round 4
// 613.453 us; speedup vs baseline: 9.9461x; 1.3313x over previous
//
#include <hip/hip_runtime.h>
#include <math.h>

constexpr int B    = 4;
constexpr int NPTS = 4096;
constexpr int CIN  = 9;
constexpr int C0   = 18;
constexpr int KNB  = 8;
constexpr int HID  = 128;
constexpr int QR   = 64;    // q rows per fmha block (16 per wave)
constexpr int KC   = 64;    // m per fmha tile
constexpr float EPSF = 1e-5f;

using f32x4  = __attribute__((ext_vector_type(4))) float;
using bf16x8 = __attribute__((ext_vector_type(8))) short;

// float -> bf16 bits, round-to-nearest-even (finite values)
__device__ inline unsigned short f2bf(float f) {
    unsigned int x = __float_as_uint(f);
    unsigned int r = (x + 0x7fffu + ((x >> 16) & 1u)) >> 16;
    return (unsigned short)r;
}
__device__ inline unsigned int pack2(float a, float b) {
    return (unsigned int)f2bf(a) | ((unsigned int)f2bf(b) << 16);
}

#define GLD_LDS16(g, l) __builtin_amdgcn_global_load_lds( \
    (const __attribute__((address_space(1))) void*)(g),   \
    (__attribute__((address_space(3))) void*)(l), 16, 0, 0)

// ---------------- pack xyz + |xyz|^2 into float4 ----------------
__global__ __launch_bounds__(256) void pack_kernel(const float* __restrict__ x,
                                                   float4* __restrict__ xyzw) {
    const int gid = blockIdx.x * 256 + threadIdx.x;   // B*NPTS
    const float* xp = x + (size_t)gid * CIN;
    const float a = xp[0], b = xp[1], c = xp[2];
    xyzw[gid] = make_float4(a, b, c, a * a + b * b + c * c);
}

// ---------------- KNN (split-scan) + local diff features ----------------
__global__ __launch_bounds__(256) void knn2_kernel(const float* __restrict__ x,
                                                   const float4* __restrict__ xyzw,
                                                   float* __restrict__ h0) {
    __shared__ __align__(16) char ldsbuf[65536];
    float4* sxy = (float4*)ldsbuf;                 // [512 j][8 c]
    const int tid = threadIdx.x;
    const int b  = blockIdx.x >> 7;
    const int p0 = (blockIdx.x & 127) << 5;        // 32 points per block
    const int p  = tid >> 3;                       // point within block
    const int c  = tid & 7;                        // chunk
    const float4* xb4 = xyzw + (size_t)b * NPTS;

#pragma unroll
    for (int i = 0; i < 16; ++i) {
        const int m = tid + i * 256;
        sxy[(m & 511) * 8 + (m >> 9)] = xb4[m];
    }
    __syncthreads();

    const int n = p0 + p;
    const float4 q4 = sxy[(n & 511) * 8 + (n >> 9)];
    const float qx = q4.x, qy = q4.y, qz = q4.z, sqn = q4.w;

    float bd[KNB];
    int   bi[KNB];
#pragma unroll
    for (int i = 0; i < KNB; ++i) { bd[i] = 3.0e38f; bi[i] = 0; }
    const float4* rowp = sxy + c;
#pragma unroll 2
    for (int j = 0; j < 512; ++j) {
        const float4 f4 = rowp[j * 8];
        const float t  = fmaf(qx, f4.x, fmaf(qy, f4.y, qz * f4.z));
        const float d2 = fmaf(-2.0f, t, sqn + f4.w);
        const int m = c * 512 + j;
        if (d2 < bd[KNB - 1] && m != n) {
            bd[KNB - 1] = d2; bi[KNB - 1] = m;
#pragma unroll
            for (int s = KNB - 1; s > 0; --s) {
                if (bd[s] < bd[s - 1]) {
                    float td = bd[s]; bd[s] = bd[s - 1]; bd[s - 1] = td;
                    int   ti = bi[s]; bi[s] = bi[s - 1]; bi[s - 1] = ti;
                }
            }
        }
    }
    __syncthreads();

    float* mbD = (float*)ldsbuf;
    int*   mbI = (int*)(ldsbuf + 8192);
    int*   idxL = (int*)(ldsbuf + 16384);
#pragma unroll
    for (int k = 0; k < KNB; ++k) {
        mbD[p * 64 + c * 8 + k] = bd[k];
        mbI[p * 64 + c * 8 + k] = bi[k];
    }
    __syncthreads();
    if (tid < 32) {
        float fd[KNB]; int fi[KNB];
#pragma unroll
        for (int i = 0; i < KNB; ++i) { fd[i] = 3.0e38f; fi[i] = 0; }
        for (int e = 0; e < 64; ++e) {
            const float d = mbD[tid * 64 + e];
            if (d < fd[KNB - 1]) {
                fd[KNB - 1] = d; fi[KNB - 1] = mbI[tid * 64 + e];
#pragma unroll
                for (int s = KNB - 1; s > 0; --s) {
                    if (fd[s] < fd[s - 1]) {
                        float td = fd[s]; fd[s] = fd[s - 1]; fd[s - 1] = td;
                        int   ti = fi[s]; fi[s] = fi[s - 1]; fi[s - 1] = ti;
                    }
                }
            }
        }
#pragma unroll
        for (int k = 0; k < KNB; ++k) idxL[tid * 8 + k] = fi[k];
    }
    __syncthreads();

    const int nb = idxL[p * 8 + c];
    const float* xb = x + (size_t)b * NPTS * CIN;
    float nv[CIN];
    const float* nbp = xb + (size_t)nb * CIN;
#pragma unroll
    for (int ch = 0; ch < CIN; ++ch) nv[ch] = nbp[ch];
#pragma unroll
    for (int d = 1; d < 8; d <<= 1) {
#pragma unroll
        for (int ch = 0; ch < CIN; ++ch) nv[ch] += __shfl_xor(nv[ch], d);
    }
    {
        const int ch = c;
        const float xv = xb[(size_t)n * CIN + ch];
        h0[((size_t)b * C0 + ch) * NPTS + n]       = nv[ch] * 0.125f - xv;
        h0[((size_t)b * C0 + CIN + ch) * NPTS + n] = xv;
    }
    if (c == 0) {
        const int ch = 8;
        const float xv = xb[(size_t)n * CIN + ch];
        h0[((size_t)b * C0 + ch) * NPTS + n]       = nv[ch] * 0.125f - xv;
        h0[((size_t)b * C0 + CIN + ch) * NPTS + n] = xv;
    }
}

// ---------------- 1x1 conv: Y[b,o,n] = sum_c W[o,c] X[b,c,n] + bias[o] ----------------
// OUTM: 0 = f32 [o][n]; 1 = bf16 [n][o] (Q,K for MFMA); 2 = bf16 [o][n] (V for MFMA)
template <int OUTM, bool RELU, bool RES>
__global__ __launch_bounds__(256) void conv_kernel(const float* __restrict__ X,
                                                   const float* __restrict__ W,
                                                   const float* __restrict__ bias,
                                                   const float* __restrict__ res,
                                                   void* __restrict__ Yv,
                                                   int C, int O) {
    __shared__ float Ws[16 * 256];
    const int b  = blockIdx.z;
    const int o_base = blockIdx.y * 16;
    const int n  = blockIdx.x * 64 + (threadIdx.x & 63);
    const int og = threadIdx.x >> 6;
    const int rows = min(16, O - o_base);
    for (int i = threadIdx.x; i < rows * C; i += 256)
        Ws[i] = W[(size_t)o_base * C + i];
    __syncthreads();
    float acc[4] = {0.f, 0.f, 0.f, 0.f};
    const float* Xp = X + (size_t)b * C * NPTS + n;
    for (int c = 0; c < C; ++c) {
        const float xv = Xp[(size_t)c * NPTS];
#pragma unroll
        for (int i = 0; i < 4; ++i)
            acc[i] = fmaf(Ws[(og * 4 + i) * C + c], xv, acc[i]);
    }
    float v[4];
#pragma unroll
    for (int i = 0; i < 4; ++i) {
        const int o = o_base + og * 4 + i;
        v[i] = acc[i] + bias[min(o, O - 1)];
        if (RES)  v[i] += res[((size_t)b * O + o) * NPTS + n];
        if (RELU) v[i] = fmaxf(v[i], 0.f);
    }
    if (OUTM == 0) {
        float* Y = (float*)Yv;
#pragma unroll
        for (int i = 0; i < 4; ++i) {
            const int o = o_base + og * 4 + i;
            if (o < O) Y[((size_t)b * O + o) * NPTS + n] = v[i];
        }
    } else if (OUTM == 1) {
        unsigned short* Y = (unsigned short*)Yv;
        ushort4 pk;
        pk.x = f2bf(v[0]); pk.y = f2bf(v[1]); pk.z = f2bf(v[2]); pk.w = f2bf(v[3]);
        *(ushort4*)(Y + ((size_t)b * NPTS + n) * O + o_base + og * 4) = pk;
    } else {
        unsigned short* Y = (unsigned short*)Yv;
#pragma unroll
        for (int i = 0; i < 4; ++i) {
            const int o = o_base + og * 4 + i;
            Y[((size_t)b * O + o) * NPTS + n] = f2bf(v[i]);
        }
    }
}

// ---------------- BN statistics ----------------
__global__ __launch_bounds__(256) void bn_stats_kernel(const float* __restrict__ Y,
                                                       float* __restrict__ mean,
                                                       float* __restrict__ istd,
                                                       int O) {
    const int o = blockIdx.x;
    const int tid = threadIdx.x;
    __shared__ double rs[256];
    __shared__ double rs2[256];
    double s = 0.0, s2 = 0.0;
    for (int i = tid; i < B * NPTS; i += 256) {
        const int bb = i >> 12;
        const int nn = i & (NPTS - 1);
        const float v = Y[((size_t)bb * O + o) * NPTS + nn];
        s  += (double)v;
        s2 += (double)v * (double)v;
    }
    rs[tid] = s; rs2[tid] = s2;
    __syncthreads();
    for (int st = 128; st > 0; st >>= 1) {
        if (tid < st) { rs[tid] += rs[tid + st]; rs2[tid] += rs2[tid + st]; }
        __syncthreads();
    }
    if (tid == 0) {
        const double M = (double)(B * NPTS);
        const double m = rs[0] / M;
        const double var = rs2[0] / M - m * m;
        mean[o] = (float)m;
        istd[o] = (float)(1.0 / sqrt(var + (double)EPSF));
    }
}

// ---------------- BN apply + ReLU ----------------
__global__ __launch_bounds__(256) void bn_relu_kernel(float* __restrict__ Y,
                                                      const float* __restrict__ g,
                                                      const float* __restrict__ be,
                                                      const float* __restrict__ mean,
                                                      const float* __restrict__ istd,
                                                      int O) {
    const size_t total = (size_t)B * O * NPTS;
    for (size_t idx = (size_t)blockIdx.x * 256 + threadIdx.x; idx < total;
         idx += (size_t)gridDim.x * 256) {
        const int o = (int)((idx / NPTS) % O);
        float v = Y[idx];
        v = g[o] * (v - mean[o]) * istd[o] + be[o];
        Y[idx] = fmaxf(v, 0.f);
    }
}

// ---------------- stage one 64x128 K tile + 128x64 V tile into LDS ----------------
// LDS layouts (16 KB each): K [64 m][16 slot*16B] phys = lin ^ ((m&7)<<4)
//                           V [128 h][8 slot*16B] phys = lin ^ ((h&7)<<4)
// global_load_lds writes linear (base + lane*16); source is inverse-swizzled.
__device__ __forceinline__ void stage_tile(char* lds, int buf,
                                           const unsigned short* Kb,
                                           const unsigned short* Vb,
                                           int n0, int w, int l) {
    char* dK = lds + buf * 16384;
    char* dV = lds + 32768 + buf * 16384;
#pragma unroll
    for (int j = 0; j < 4; ++j) {
        const int y = w * 4096 + j * 1024 + l * 16;
        const int m = y >> 8;
        const int slot = ((y >> 4) & 15) ^ (m & 7);
        const unsigned short* src = Kb + (size_t)(n0 + m) * HID + slot * 8;
        GLD_LDS16(src, dK + w * 4096 + j * 1024);
    }
#pragma unroll
    for (int j = 0; j < 4; ++j) {
        const int y = w * 4096 + j * 1024 + l * 16;
        const int h = y >> 7;
        const int slot = ((y >> 4) & 7) ^ (h & 7);
        const unsigned short* src = Vb + (size_t)h * NPTS + n0 + slot * 8;
        GLD_LDS16(src, dV + w * 4096 + j * 1024);
    }
}

// ---------------- MFMA flash attention, one-pass online softmax, KV-split x2 ----------------
// Writes unnormalized Acc[b][128][N] per split + per-q running max M and sum L.
__global__ __launch_bounds__(256) void fmha2_kernel(const unsigned short* __restrict__ Qg,
                                                    const unsigned short* __restrict__ Kg,
                                                    const unsigned short* __restrict__ Vg,
                                                    float* __restrict__ A0, float* __restrict__ A1,
                                                    float* __restrict__ M0, float* __restrict__ L0,
                                                    float* __restrict__ M1, float* __restrict__ L1) {
    __shared__ __align__(16) char lds[73728];   // K dbuf 32K | V dbuf 32K | P 4x2K
    const int tid = threadIdx.x;
    const int w = tid >> 6, l = tid & 63;
    const int lg = l >> 4, lq = l & 15;
    const int b  = blockIdx.y;
    const int q0 = blockIdx.x * QR;
    const int split = blockIdx.z;
    const int n0base = split * (NPTS / 2);
    float* Ap = split ? A1 : A0;
    float* Mp = split ? M1 : M0;
    float* Lp = split ? L1 : L0;
    char* ldsP = lds + 65536 + w * 2048;

    // Q fragments (B-operand): lane holds Q[q=lq][k=ks*32+lg*8+i]
    bf16x8 qf[4];
    {
        const unsigned short* qp = Qg + ((size_t)b * NPTS + q0 + w * 16 + lq) * HID + lg * 8;
#pragma unroll
        for (int ks = 0; ks < 4; ++ks)
            qf[ks] = *(const bf16x8*)(qp + ks * 32);
    }
    const unsigned short* Kb = Kg + (size_t)b * NPTS * HID;
    const unsigned short* Vb = Vg + (size_t)b * HID * NPTS;

    float m_r = -3.0e38f;      // running max for q=lq (uniform across lg)
    float lsum = 0.f;          // partial exp-sum for q=lq over this lane's m subset
    f32x4 oacc[8];
#pragma unroll
    for (int hs = 0; hs < 8; ++hs) oacc[hs] = {0.f, 0.f, 0.f, 0.f};

    constexpr int NT = (NPTS / 2) / KC;   // 32 tiles per split
    stage_tile(lds, 0, Kb, Vb, n0base, w, l);

    for (int t = 0; t < NT; ++t) {
        const int cur = t & 1;
        __syncthreads();                              // tile t staged; buffers free
        if (t + 1 < NT)
            stage_tile(lds, cur ^ 1, Kb, Vb, n0base + (t + 1) * KC, w, l);
        char* ldsK = lds + cur * 16384;
        char* ldsV = lds + 32768 + cur * 16384;

        // ---- QK^T: S[m][q], m = ms*16 + lg*4 + r, q = lq ----
        f32x4 sv[4];
        __builtin_amdgcn_s_setprio(1);
#pragma unroll
        for (int ms = 0; ms < 4; ++ms) {
            const int row = ms * 16 + lq;
            f32x4 s = {0.f, 0.f, 0.f, 0.f};
#pragma unroll
            for (int ks = 0; ks < 4; ++ks) {
                bf16x8 kf = *(const bf16x8*)(ldsK + ((row * 256 + ks * 64 + lg * 16) ^ ((row & 7) << 4)));
                s = __builtin_amdgcn_mfma_f32_16x16x32_bf16(kf, qf[ks], s, 0, 0, 0);
            }
            sv[ms] = s;
        }
        __builtin_amdgcn_s_setprio(0);

        // ---- tile max for q=lq (reduce 16 regs + across lg groups) ----
        float pmax = sv[0][0];
#pragma unroll
        for (int ms = 0; ms < 4; ++ms)
#pragma unroll
            for (int r = 0; r < 4; ++r) pmax = fmaxf(pmax, sv[ms][r]);
        pmax = fmaxf(pmax, __shfl_xor(pmax, 16));
        pmax = fmaxf(pmax, __shfl_xor(pmax, 32));

        // ---- deferred rescale (THR=8) ----
        if (__any(pmax > m_r + 8.0f)) {
            const float newm = fmaxf(m_r, pmax);
            const float sc = __expf(m_r - newm);     // scale for q=lq
            lsum *= sc;
            float sc_r[4];
#pragma unroll
            for (int r = 0; r < 4; ++r) sc_r[r] = __shfl(sc, lg * 4 + r);  // scale for q=lg*4+r
#pragma unroll
            for (int hs = 0; hs < 8; ++hs)
#pragma unroll
                for (int r = 0; r < 4; ++r) oacc[hs][r] *= sc_r[r];
            m_r = newm;
        }

        // ---- exp + P -> LDS (bf16) ----
#pragma unroll
        for (int ms = 0; ms < 4; ++ms) {
            const float p0 = __expf(sv[ms][0] - m_r);
            const float p1 = __expf(sv[ms][1] - m_r);
            const float p2 = __expf(sv[ms][2] - m_r);
            const float p3 = __expf(sv[ms][3] - m_r);
            lsum += (p0 + p1) + (p2 + p3);
            const int lin = lq * 128 + ms * 32 + lg * 8;
            const int ad  = lin ^ ((lq & 7) << 4);
            *(unsigned int*)(ldsP + ad)     = pack2(p0, p1);
            *(unsigned int*)(ldsP + ad + 4) = pack2(p2, p3);
        }

        // ---- PV: O[h][q] += P[q][m] V[h][m] ----
        __builtin_amdgcn_s_setprio(1);
#pragma unroll
        for (int msl = 0; msl < 2; ++msl) {
            bf16x8 pf = *(const bf16x8*)(ldsP + ((lq * 128 + msl * 64 + lg * 16) ^ ((lq & 7) << 4)));
#pragma unroll
            for (int hs = 0; hs < 8; ++hs) {
                const int hrow = hs * 16 + lq;
                bf16x8 vf = *(const bf16x8*)(ldsV + ((hrow * 128 + msl * 64 + lg * 16) ^ ((hrow & 7) << 4)));
                oacc[hs] = __builtin_amdgcn_mfma_f32_16x16x32_bf16(pf, vf, oacc[hs], 0, 0, 0);
            }
        }
        __builtin_amdgcn_s_setprio(0);
    }

    // ---- finalize: reduce lsum across lg; write Acc (unnormalized) + M/L ----
    lsum += __shfl_xor(lsum, 16);
    lsum += __shfl_xor(lsum, 32);
    float* Ab = Ap + (size_t)b * HID * NPTS + q0 + w * 16;
#pragma unroll
    for (int hs = 0; hs < 8; ++hs) {
#pragma unroll
        for (int r = 0; r < 4; ++r)
            Ab[(size_t)(hs * 16 + lq) * NPTS + lg * 4 + r] = oacc[hs][r];
    }
    if (lg == 0) {
        Mp[b * NPTS + q0 + w * 16 + lq] = m_r;
        Lp[b * NPTS + q0 + w * 16 + lq] = lsum;
    }
}

// ---------------- combine the two KV-split partials (in place into A0) ----------------
__global__ __launch_bounds__(256) void fmha_combine_kernel(float* __restrict__ A0,
                                                           const float* __restrict__ A1,
                                                           const float* __restrict__ M0,
                                                           const float* __restrict__ L0,
                                                           const float* __restrict__ M1,
                                                           const float* __restrict__ L1) {
    const int i = blockIdx.x * 256 + threadIdx.x;    // B*HID*NPTS
    const int n = i & (NPTS - 1);
    const int b = i >> 19;                           // 128*4096 = 2^19
    const float m0 = M0[b * NPTS + n], m1 = M1[b * NPTS + n];
    const float l0 = L0[b * NPTS + n], l1 = L1[b * NPTS + n];
    const float M = fmaxf(m0, m1);
    const float e0 = __expf(m0 - M), e1 = __expf(m1 - M);
    const float inv = 1.0f / (e0 * l0 + e1 * l1);
    A0[i] = (e0 * A0[i] + e1 * A1[i]) * inv;
}

// ---------------- softmax over N of pooling scores ----------------
__global__ __launch_bounds__(256) void softmax_w_kernel(float* __restrict__ s) {
    const int b = blockIdx.x;
    const int tid = threadIdx.x;
    __shared__ float red[256];
    float lm = -3.0e38f;
    for (int n = tid; n < NPTS; n += 256) lm = fmaxf(lm, s[b * NPTS + n]);
    red[tid] = lm;
    __syncthreads();
    for (int st = 128; st > 0; st >>= 1) {
        if (tid < st) red[tid] = fmaxf(red[tid], red[tid + st]);
        __syncthreads();
    }
    const float mx = red[0];
    __syncthreads();
    float ls = 0.f;
    for (int n = tid; n < NPTS; n += 256) {
        const float p = __expf(s[b * NPTS + n] - mx);
        s[b * NPTS + n] = p;
        ls += p;
    }
    red[tid] = ls;
    __syncthreads();
    for (int st = 128; st > 0; st >>= 1) {
        if (tid < st) red[tid] += red[tid + st];
        __syncthreads();
    }
    const float inv = 1.f / red[0];
    __syncthreads();
    for (int n = tid; n < NPTS; n += 256) s[b * NPTS + n] *= inv;
}

// ---------------- weighted pooling ----------------
__global__ __launch_bounds__(256) void pool_kernel(const float* __restrict__ h,
                                                   const float* __restrict__ w,
                                                   float* __restrict__ pooled) {
    const int c = blockIdx.x, b = blockIdx.y, tid = threadIdx.x;
    __shared__ float red[256];
    const float* hp = h + ((size_t)b * 256 + c) * NPTS;
    const float* wp = w + (size_t)b * NPTS;
    float acc = 0.f;
    for (int n = tid; n < NPTS; n += 256) acc = fmaf(hp[n], wp[n], acc);
    red[tid] = acc;
    __syncthreads();
    for (int st = 128; st > 0; st >>= 1) {
        if (tid < st) red[tid] += red[tid + st];
        __syncthreads();
    }
    if (tid == 0) pooled[b * 256 + c] = red[0];
}

// ---------------- final FC + ReLU ----------------
__global__ __launch_bounds__(256) void fc_kernel(const float* __restrict__ pooled,
                                                 const float* __restrict__ fcw,
                                                 const float* __restrict__ fcb,
                                                 float* __restrict__ out) {
    const int b = blockIdx.x, j = threadIdx.x;
    __shared__ float ps[256];
    ps[j] = pooled[b * 256 + j];
    __syncthreads();
    float acc = fcb[j];
    for (int c = 0; c < 256; ++c) acc = fmaf(ps[c], fcw[j * 256 + c], acc);
    out[b * 256 + j] = fmaxf(acc, 0.f);
}

extern "C" void kernel_launch(void* const* d_in, const int* in_sizes, int n_in,
                              void* d_out, int out_size, void* d_ws, size_t ws_size,
                              hipStream_t stream) {
    const float* x   = (const float*)d_in[0];
    const float* w1  = (const float*)d_in[1];
    const float* b1  = (const float*)d_in[2];
    const float* g1  = (const float*)d_in[3];
    const float* be1 = (const float*)d_in[4];
    const float* w2  = (const float*)d_in[5];
    const float* b2  = (const float*)d_in[6];
    const float* g2  = (const float*)d_in[7];
    const float* be2 = (const float*)d_in[8];
    const float* w3  = (const float*)d_in[9];
    const float* b3  = (const float*)d_in[10];
    const float* g3  = (const float*)d_in[11];
    const float* be3 = (const float*)d_in[12];
    const float* qw  = (const float*)d_in[13];
    const float* qb  = (const float*)d_in[14];
    const float* kw  = (const float*)d_in[15];
    const float* kb  = (const float*)d_in[16];
    const float* vw  = (const float*)d_in[17];
    const float* vb  = (const float*)d_in[18];
    const float* fw  = (const float*)d_in[19];
    const float* fb  = (const float*)d_in[20];
    const float* aw1 = (const float*)d_in[21];
    const float* ab1 = (const float*)d_in[22];
    const float* aw2 = (const float*)d_in[23];
    const float* ab2 = (const float*)d_in[24];
    const float* fcw = (const float*)d_in[25];
    const float* fcb = (const float*)d_in[26];

    float* ws = (float*)d_ws;
    float* h0 = ws;                     // 4*18*4096   (aliased later: M/L arrays)
    float* h1 = h0 + 294912;            // 4*64*4096   (aliased later: Acc1, 8 MB of 12.6)
    float* h2 = h1 + 1048576;           // 4*128*4096
    float* h3 = h2 + 2097152;           // 4*256*4096
    float* Q  = h3 + 4194304;           // bf16 [B][N][128]
    float* K  = Q  + 2097152;
    float* V  = K  + 2097152;
    float* Oa = V  + 2097152;           // f32 [B][128][N] = Acc0 / combined O
    float* h4 = Oa + 2097152;           // 4*256*4096
    float* a  = h4 + 4194304;
    float* s  = a  + 1048576;
    float* pooled = s + 16384;
    float* mean   = pooled + 1024;
    float* istd   = mean + 256;
    float4* xyzw  = (float4*)(istd + 256);   // B*NPTS float4

    unsigned short* Qb = (unsigned short*)Q;
    unsigned short* Kb = (unsigned short*)K;
    unsigned short* Vb = (unsigned short*)V;

    // fmha split aliases (dead buffers at fmha time)
    float* Acc1 = h1;                   // 8 MB (h1+h2 span 12.6 MB)
    float* M0   = h0;
    float* L0   = h0 + 16384;
    float* M1   = h0 + 32768;
    float* L1   = h0 + 49152;

    pack_kernel<<<dim3(B * NPTS / 256), 256, 0, stream>>>(x, xyzw);
    knn2_kernel<<<dim3(B * NPTS / 32), 256, 0, stream>>>(x, xyzw, h0);

    // layer 1: 18 -> 64
    conv_kernel<0, false, false><<<dim3(NPTS / 64, 4, B), 256, 0, stream>>>(h0, w1, b1, nullptr, h1, C0, 64);
    bn_stats_kernel<<<64, 256, 0, stream>>>(h1, mean, istd, 64);
    bn_relu_kernel<<<2048, 256, 0, stream>>>(h1, g1, be1, mean, istd, 64);
    // layer 2: 64 -> 128
    conv_kernel<0, false, false><<<dim3(NPTS / 64, 8, B), 256, 0, stream>>>(h1, w2, b2, nullptr, h2, 64, 128);
    bn_stats_kernel<<<128, 256, 0, stream>>>(h2, mean, istd, 128);
    bn_relu_kernel<<<2048, 256, 0, stream>>>(h2, g2, be2, mean, istd, 128);
    // layer 3: 128 -> 256
    conv_kernel<0, false, false><<<dim3(NPTS / 64, 16, B), 256, 0, stream>>>(h2, w3, b3, nullptr, h3, 128, 256);
    bn_stats_kernel<<<256, 256, 0, stream>>>(h3, mean, istd, 256);
    bn_relu_kernel<<<2048, 256, 0, stream>>>(h3, g3, be3, mean, istd, 256);

    // Q, K projections -> bf16 [n][h]; V -> bf16 [h][n]
    conv_kernel<1, false, false><<<dim3(NPTS / 64, 8, B), 256, 0, stream>>>(h3, qw, qb, nullptr, Qb, 256, 128);
    conv_kernel<1, false, false><<<dim3(NPTS / 64, 8, B), 256, 0, stream>>>(h3, kw, kb, nullptr, Kb, 256, 128);
    conv_kernel<2, false, false><<<dim3(NPTS / 64, 8, B), 256, 0, stream>>>(h3, vw, vb, nullptr, Vb, 256, 128);

    fmha2_kernel<<<dim3(NPTS / QR, B, 2), 256, 0, stream>>>(Qb, Kb, Vb, Oa, Acc1, M0, L0, M1, L1);
    fmha_combine_kernel<<<dim3(B * HID * NPTS / 256), 256, 0, stream>>>(Oa, Acc1, M0, L0, M1, L1);

    // fuse-out conv + residual: 128 -> 256, + h3
    conv_kernel<0, false, true><<<dim3(NPTS / 64, 16, B), 256, 0, stream>>>(Oa, fw, fb, h3, h4, 128, 256);
    // attention-pool MLP
    conv_kernel<0, true, false><<<dim3(NPTS / 64, 4, B), 256, 0, stream>>>(h4, aw1, ab1, nullptr, a, 256, 64);
    conv_kernel<0, false, false><<<dim3(NPTS / 64, 1, B), 256, 0, stream>>>(a, aw2, ab2, nullptr, s, 64, 1);

    softmax_w_kernel<<<B, 256, 0, stream>>>(s);
    pool_kernel<<<dim3(256, B), 256, 0, stream>>>(h4, s, pooled);
    fc_kernel<<<B, 256, 0, stream>>>(pooled, fcw, fcb, (float*)d_out);

    (void)in_sizes; (void)n_in; (void)out_size; (void)ws_size;
}

// Round 5
// 481.718 us; speedup vs baseline: 12.6661x; 1.2735x over previous
//
#include <hip/hip_runtime.h>
#include <math.h>

constexpr int B    = 4;
constexpr int NPTS = 4096;
constexpr int CIN  = 9;
constexpr int C0   = 18;
constexpr int KNB  = 8;
constexpr int HID  = 128;
constexpr int QR   = 64;    // q rows per fmha block (16 per wave)
constexpr int KC   = 64;    // m per fmha tile
constexpr float EPSF = 1e-5f;

using f32x4  = __attribute__((ext_vector_type(4))) float;
using bf16x8 = __attribute__((ext_vector_type(8))) short;

// float -> bf16 bits, round-to-nearest-even (finite values)
__device__ inline unsigned short f2bf(float f) {
    unsigned int x = __float_as_uint(f);
    unsigned int r = (x + 0x7fffu + ((x >> 16) & 1u)) >> 16;
    return (unsigned short)r;
}
__device__ inline unsigned int pack2(float a, float b) {
    return (unsigned int)f2bf(a) | ((unsigned int)f2bf(b) << 16);
}

#define GLD_LDS16(g, l) __builtin_amdgcn_global_load_lds( \
    (const __attribute__((address_space(1))) void*)(g),   \
    (__attribute__((address_space(3))) void*)(l), 16, 0, 0)

// ---------------- pack xyz + |xyz|^2 into float4 ----------------
__global__ __launch_bounds__(256) void pack_kernel(const float* __restrict__ x,
                                                   float4* __restrict__ xyzw) {
    const int gid = blockIdx.x * 256 + threadIdx.x;   // B*NPTS
    const float* xp = x + (size_t)gid * CIN;
    const float a = xp[0], b = xp[1], c = xp[2];
    xyzw[gid] = make_float4(a, b, c, a * a + b * b + c * c);
}

// ---------------- KNN v3: 8 points/block, 32 chunks/point, tiled LDS ----------------
// grid: B*NPTS/8 = 2048 blocks, 256 threads. LDS: 2 x 8KB tile buffers.
// Tile slot idx holds candidate m = idx ^ ((idx>>4)&7)  (bank-spread swizzle).
__global__ __launch_bounds__(256) void knn3_kernel(const float* __restrict__ x,
                                                   const float4* __restrict__ xyzw,
                                                   float* __restrict__ h0) {
    __shared__ __align__(16) char lds[16384];
    const int tid = threadIdx.x;
    const int w = tid >> 6, l = tid & 63;
    const int b  = blockIdx.x >> 9;             // 512 blocks per batch
    const int p0 = (blockIdx.x & 511) << 3;     // 8 points per block
    const int c  = l & 31;                      // chunk within point
    const int p  = w * 2 + (l >> 5);            // point within block
    const int n  = p0 + p;
    const float4* xb4 = xyzw + (size_t)b * NPTS;

    const float4 q4 = xb4[n];
    const float qx = q4.x, qy = q4.y, qz = q4.z, sqn = q4.w;

    float bd[KNB];
    int   bi[KNB];
#pragma unroll
    for (int i = 0; i < KNB; ++i) { bd[i] = 3.0e38f; bi[i] = 0; }

    // stage tile t (512 cands, 8KB) into buffer buf; dest linear, source inverse-swizzled
    auto stage = [&](int buf, int t) {
#pragma unroll
        for (int i = 0; i < 2; ++i) {
            const int idx = i * 256 + w * 64 + l;
            const int m   = idx ^ ((idx >> 4) & 7);
            GLD_LDS16(xb4 + (size_t)t * 512 + m, lds + buf * 8192 + i * 4096 + w * 1024);
        }
    };

    stage(0, 0);
    for (int t = 0; t < 8; ++t) {
        const int cur = t & 1;
        __syncthreads();                        // tile t resident (barrier drains vmcnt)
        if (t < 7) stage(cur ^ 1, t + 1);       // prefetch next under the scan

        // shared gate: min of the point's 32 running 8th-bests (safe filter:
        // each bd[7] >= final global 8th, so no true top-8 member is gated out)
        float thr = bd[KNB - 1];
        thr = fminf(thr, __shfl_xor(thr, 1));
        thr = fminf(thr, __shfl_xor(thr, 2));
        thr = fminf(thr, __shfl_xor(thr, 4));
        thr = fminf(thr, __shfl_xor(thr, 8));
        thr = fminf(thr, __shfl_xor(thr, 16));

        const char* buf = lds + cur * 8192 + c * 256;
        const int mbase = t * 512 + c * 16;
        const int cswz  = (c & 7) << 4;
#pragma unroll 4
        for (int j = 0; j < 16; ++j) {
            const float4 f4 = *(const float4*)(buf + ((j << 4) ^ cswz));
            const float tt = fmaf(qx, f4.x, fmaf(qy, f4.y, qz * f4.z));
            const float d2 = fmaf(-2.0f, tt, sqn + f4.w);
            const int m = mbase + j;
            const float gate = fminf(thr, bd[KNB - 1]);
            if (d2 < gate && m != n) {
                bd[KNB - 1] = d2; bi[KNB - 1] = m;
#pragma unroll
                for (int s = KNB - 1; s > 0; --s) {
                    if (bd[s] < bd[s - 1]) {
                        float td = bd[s]; bd[s] = bd[s - 1]; bd[s - 1] = td;
                        int   ti = bi[s]; bi[s] = bi[s - 1]; bi[s - 1] = ti;
                    }
                }
            }
        }
    }

    // tournament merge: 8 rounds of 32-lane argmin over sorted list heads
    int res[KNB];
    const int lh = l & 31;
#pragma unroll
    for (int r = 0; r < KNB; ++r) {
        float hd = bd[0]; int hb = bi[0]; int hl = lh;
#pragma unroll
        for (int mask = 16; mask > 0; mask >>= 1) {
            const float od = __shfl_xor(hd, mask);
            const int   ob = __shfl_xor(hb, mask);
            const int   ol = __shfl_xor(hl, mask);
            if (od < hd || (od == hd && ol < hl)) { hd = od; hb = ob; hl = ol; }
        }
        res[r] = hb;
        if (lh == hl) {
#pragma unroll
            for (int s = 0; s < KNB - 1; ++s) { bd[s] = bd[s + 1]; bi[s] = bi[s + 1]; }
            bd[KNB - 1] = 3.0e38f;
        }
    }

    // gather: lane (c&7)=k loads neighbor res[k]'s 9 channels, butterfly-sum over 8 lanes
    const int c8 = c & 7;
    int nb = res[0];
#pragma unroll
    for (int k = 1; k < KNB; ++k) nb = (c8 == k) ? res[k] : nb;
    const float* xb = x + (size_t)b * NPTS * CIN;
    float nv[CIN];
    const float* nbp = xb + (size_t)nb * CIN;
#pragma unroll
    for (int ch = 0; ch < CIN; ++ch) nv[ch] = nbp[ch];
#pragma unroll
    for (int d = 1; d < 8; d <<= 1) {
#pragma unroll
        for (int ch = 0; ch < CIN; ++ch) nv[ch] += __shfl_xor(nv[ch], d);
    }
    const int ch = min(c, 8);
    float nvc = nv[0];
#pragma unroll
    for (int k = 1; k < CIN; ++k) nvc = (ch == k) ? nv[k] : nvc;
    if (c < 9) {
        const float xv = xb[(size_t)n * CIN + ch];
        h0[((size_t)b * C0 + ch) * NPTS + n]       = nvc * 0.125f - xv;
        h0[((size_t)b * C0 + CIN + ch) * NPTS + n] = xv;
    }
}

// ---------------- 1x1 conv: Y[b,o,n] = sum_c W[o,c] X[b,c,n] + bias[o] ----------------
// OUTM: 0 = f32 [o][n]; 1 = bf16 [n][o] (Q,K for MFMA); 2 = bf16 [o][n] (V for MFMA)
template <int OUTM, bool RELU, bool RES>
__global__ __launch_bounds__(256) void conv_kernel(const float* __restrict__ X,
                                                   const float* __restrict__ W,
                                                   const float* __restrict__ bias,
                                                   const float* __restrict__ res,
                                                   void* __restrict__ Yv,
                                                   int C, int O) {
    __shared__ float Ws[16 * 256];
    const int b  = blockIdx.z;
    const int o_base = blockIdx.y * 16;
    const int n  = blockIdx.x * 64 + (threadIdx.x & 63);
    const int og = threadIdx.x >> 6;
    const int rows = min(16, O - o_base);
    for (int i = threadIdx.x; i < rows * C; i += 256)
        Ws[i] = W[(size_t)o_base * C + i];
    __syncthreads();
    float acc[4] = {0.f, 0.f, 0.f, 0.f};
    const float* Xp = X + (size_t)b * C * NPTS + n;
    for (int c = 0; c < C; ++c) {
        const float xv = Xp[(size_t)c * NPTS];
#pragma unroll
        for (int i = 0; i < 4; ++i)
            acc[i] = fmaf(Ws[(og * 4 + i) * C + c], xv, acc[i]);
    }
    float v[4];
#pragma unroll
    for (int i = 0; i < 4; ++i) {
        const int o = o_base + og * 4 + i;
        v[i] = acc[i] + bias[min(o, O - 1)];
        if (RES)  v[i] += res[((size_t)b * O + o) * NPTS + n];
        if (RELU) v[i] = fmaxf(v[i], 0.f);
    }
    if (OUTM == 0) {
        float* Y = (float*)Yv;
#pragma unroll
        for (int i = 0; i < 4; ++i) {
            const int o = o_base + og * 4 + i;
            if (o < O) Y[((size_t)b * O + o) * NPTS + n] = v[i];
        }
    } else if (OUTM == 1) {
        unsigned short* Y = (unsigned short*)Yv;
        ushort4 pk;
        pk.x = f2bf(v[0]); pk.y = f2bf(v[1]); pk.z = f2bf(v[2]); pk.w = f2bf(v[3]);
        *(ushort4*)(Y + ((size_t)b * NPTS + n) * O + o_base + og * 4) = pk;
    } else {
        unsigned short* Y = (unsigned short*)Yv;
#pragma unroll
        for (int i = 0; i < 4; ++i) {
            const int o = o_base + og * 4 + i;
            Y[((size_t)b * O + o) * NPTS + n] = f2bf(v[i]);
        }
    }
}

// ---------------- BN statistics ----------------
__global__ __launch_bounds__(256) void bn_stats_kernel(const float* __restrict__ Y,
                                                       float* __restrict__ mean,
                                                       float* __restrict__ istd,
                                                       int O) {
    const int o = blockIdx.x;
    const int tid = threadIdx.x;
    __shared__ double rs[256];
    __shared__ double rs2[256];
    double s = 0.0, s2 = 0.0;
    for (int i = tid; i < B * NPTS; i += 256) {
        const int bb = i >> 12;
        const int nn = i & (NPTS - 1);
        const float v = Y[((size_t)bb * O + o) * NPTS + nn];
        s  += (double)v;
        s2 += (double)v * (double)v;
    }
    rs[tid] = s; rs2[tid] = s2;
    __syncthreads();
    for (int st = 128; st > 0; st >>= 1) {
        if (tid < st) { rs[tid] += rs[tid + st]; rs2[tid] += rs2[tid + st]; }
        __syncthreads();
    }
    if (tid == 0) {
        const double M = (double)(B * NPTS);
        const double m = rs[0] / M;
        const double var = rs2[0] / M - m * m;
        mean[o] = (float)m;
        istd[o] = (float)(1.0 / sqrt(var + (double)EPSF));
    }
}

// ---------------- BN apply + ReLU ----------------
__global__ __launch_bounds__(256) void bn_relu_kernel(float* __restrict__ Y,
                                                      const float* __restrict__ g,
                                                      const float* __restrict__ be,
                                                      const float* __restrict__ mean,
                                                      const float* __restrict__ istd,
                                                      int O) {
    const size_t total = (size_t)B * O * NPTS;
    for (size_t idx = (size_t)blockIdx.x * 256 + threadIdx.x; idx < total;
         idx += (size_t)gridDim.x * 256) {
        const int o = (int)((idx / NPTS) % O);
        float v = Y[idx];
        v = g[o] * (v - mean[o]) * istd[o] + be[o];
        Y[idx] = fmaxf(v, 0.f);
    }
}

// ---------------- stage one 64x128 K tile + 128x64 V tile into LDS ----------------
__device__ __forceinline__ void stage_tile(char* lds, int buf,
                                           const unsigned short* Kb,
                                           const unsigned short* Vb,
                                           int n0, int w, int l) {
    char* dK = lds + buf * 16384;
    char* dV = lds + 32768 + buf * 16384;
#pragma unroll
    for (int j = 0; j < 4; ++j) {
        const int y = w * 4096 + j * 1024 + l * 16;
        const int m = y >> 8;
        const int slot = ((y >> 4) & 15) ^ (m & 7);
        const unsigned short* src = Kb + (size_t)(n0 + m) * HID + slot * 8;
        GLD_LDS16(src, dK + w * 4096 + j * 1024);
    }
#pragma unroll
    for (int j = 0; j < 4; ++j) {
        const int y = w * 4096 + j * 1024 + l * 16;
        const int h = y >> 7;
        const int slot = ((y >> 4) & 7) ^ (h & 7);
        const unsigned short* src = Vb + (size_t)h * NPTS + n0 + slot * 8;
        GLD_LDS16(src, dV + w * 4096 + j * 1024);
    }
}

// ---------------- MFMA flash attention, one-pass online softmax, KV-split x2 ----------------
__global__ __launch_bounds__(256) void fmha2_kernel(const unsigned short* __restrict__ Qg,
                                                    const unsigned short* __restrict__ Kg,
                                                    const unsigned short* __restrict__ Vg,
                                                    float* __restrict__ A0, float* __restrict__ A1,
                                                    float* __restrict__ M0, float* __restrict__ L0,
                                                    float* __restrict__ M1, float* __restrict__ L1) {
    __shared__ __align__(16) char lds[73728];   // K dbuf 32K | V dbuf 32K | P 4x2K
    const int tid = threadIdx.x;
    const int w = tid >> 6, l = tid & 63;
    const int lg = l >> 4, lq = l & 15;
    const int b  = blockIdx.y;
    const int q0 = blockIdx.x * QR;
    const int split = blockIdx.z;
    const int n0base = split * (NPTS / 2);
    float* Ap = split ? A1 : A0;
    float* Mp = split ? M1 : M0;
    float* Lp = split ? L1 : L0;
    char* ldsP = lds + 65536 + w * 2048;

    bf16x8 qf[4];
    {
        const unsigned short* qp = Qg + ((size_t)b * NPTS + q0 + w * 16 + lq) * HID + lg * 8;
#pragma unroll
        for (int ks = 0; ks < 4; ++ks)
            qf[ks] = *(const bf16x8*)(qp + ks * 32);
    }
    const unsigned short* Kb = Kg + (size_t)b * NPTS * HID;
    const unsigned short* Vb = Vg + (size_t)b * HID * NPTS;

    float m_r = -3.0e38f;
    float lsum = 0.f;
    f32x4 oacc[8];
#pragma unroll
    for (int hs = 0; hs < 8; ++hs) oacc[hs] = {0.f, 0.f, 0.f, 0.f};

    constexpr int NT = (NPTS / 2) / KC;
    stage_tile(lds, 0, Kb, Vb, n0base, w, l);

    for (int t = 0; t < NT; ++t) {
        const int cur = t & 1;
        __syncthreads();
        if (t + 1 < NT)
            stage_tile(lds, cur ^ 1, Kb, Vb, n0base + (t + 1) * KC, w, l);
        char* ldsK = lds + cur * 16384;
        char* ldsV = lds + 32768 + cur * 16384;

        f32x4 sv[4];
        __builtin_amdgcn_s_setprio(1);
#pragma unroll
        for (int ms = 0; ms < 4; ++ms) {
            const int row = ms * 16 + lq;
            f32x4 s = {0.f, 0.f, 0.f, 0.f};
#pragma unroll
            for (int ks = 0; ks < 4; ++ks) {
                bf16x8 kf = *(const bf16x8*)(ldsK + ((row * 256 + ks * 64 + lg * 16) ^ ((row & 7) << 4)));
                s = __builtin_amdgcn_mfma_f32_16x16x32_bf16(kf, qf[ks], s, 0, 0, 0);
            }
            sv[ms] = s;
        }
        __builtin_amdgcn_s_setprio(0);

        float pmax = sv[0][0];
#pragma unroll
        for (int ms = 0; ms < 4; ++ms)
#pragma unroll
            for (int r = 0; r < 4; ++r) pmax = fmaxf(pmax, sv[ms][r]);
        pmax = fmaxf(pmax, __shfl_xor(pmax, 16));
        pmax = fmaxf(pmax, __shfl_xor(pmax, 32));

        if (__any(pmax > m_r + 8.0f)) {
            const float newm = fmaxf(m_r, pmax);
            const float sc = __expf(m_r - newm);
            lsum *= sc;
            float sc_r[4];
#pragma unroll
            for (int r = 0; r < 4; ++r) sc_r[r] = __shfl(sc, lg * 4 + r);
#pragma unroll
            for (int hs = 0; hs < 8; ++hs)
#pragma unroll
                for (int r = 0; r < 4; ++r) oacc[hs][r] *= sc_r[r];
            m_r = newm;
        }

#pragma unroll
        for (int ms = 0; ms < 4; ++ms) {
            const float p0 = __expf(sv[ms][0] - m_r);
            const float p1 = __expf(sv[ms][1] - m_r);
            const float p2 = __expf(sv[ms][2] - m_r);
            const float p3 = __expf(sv[ms][3] - m_r);
            lsum += (p0 + p1) + (p2 + p3);
            const int lin = lq * 128 + ms * 32 + lg * 8;
            const int ad  = lin ^ ((lq & 7) << 4);
            *(unsigned int*)(ldsP + ad)     = pack2(p0, p1);
            *(unsigned int*)(ldsP + ad + 4) = pack2(p2, p3);
        }

        __builtin_amdgcn_s_setprio(1);
#pragma unroll
        for (int msl = 0; msl < 2; ++msl) {
            bf16x8 pf = *(const bf16x8*)(ldsP + ((lq * 128 + msl * 64 + lg * 16) ^ ((lq & 7) << 4)));
#pragma unroll
            for (int hs = 0; hs < 8; ++hs) {
                const int hrow = hs * 16 + lq;
                bf16x8 vf = *(const bf16x8*)(ldsV + ((hrow * 128 + msl * 64 + lg * 16) ^ ((hrow & 7) << 4)));
                oacc[hs] = __builtin_amdgcn_mfma_f32_16x16x32_bf16(pf, vf, oacc[hs], 0, 0, 0);
            }
        }
        __builtin_amdgcn_s_setprio(0);
    }

    lsum += __shfl_xor(lsum, 16);
    lsum += __shfl_xor(lsum, 32);
    float* Ab = Ap + (size_t)b * HID * NPTS + q0 + w * 16;
#pragma unroll
    for (int hs = 0; hs < 8; ++hs) {
#pragma unroll
        for (int r = 0; r < 4; ++r)
            Ab[(size_t)(hs * 16 + lq) * NPTS + lg * 4 + r] = oacc[hs][r];
    }
    if (lg == 0) {
        Mp[b * NPTS + q0 + w * 16 + lq] = m_r;
        Lp[b * NPTS + q0 + w * 16 + lq] = lsum;
    }
}

// ---------------- combine the two KV-split partials (in place into A0) ----------------
__global__ __launch_bounds__(256) void fmha_combine_kernel(float* __restrict__ A0,
                                                           const float* __restrict__ A1,
                                                           const float* __restrict__ M0,
                                                           const float* __restrict__ L0,
                                                           const float* __restrict__ M1,
                                                           const float* __restrict__ L1) {
    const int i = blockIdx.x * 256 + threadIdx.x;
    const int n = i & (NPTS - 1);
    const int b = i >> 19;
    const float m0 = M0[b * NPTS + n], m1 = M1[b * NPTS + n];
    const float l0 = L0[b * NPTS + n], l1 = L1[b * NPTS + n];
    const float M = fmaxf(m0, m1);
    const float e0 = __expf(m0 - M), e1 = __expf(m1 - M);
    const float inv = 1.0f / (e0 * l0 + e1 * l1);
    A0[i] = (e0 * A0[i] + e1 * A1[i]) * inv;
}

// ---------------- softmax over N of pooling scores ----------------
__global__ __launch_bounds__(256) void softmax_w_kernel(float* __restrict__ s) {
    const int b = blockIdx.x;
    const int tid = threadIdx.x;
    __shared__ float red[256];
    float lm = -3.0e38f;
    for (int n = tid; n < NPTS; n += 256) lm = fmaxf(lm, s[b * NPTS + n]);
    red[tid] = lm;
    __syncthreads();
    for (int st = 128; st > 0; st >>= 1) {
        if (tid < st) red[tid] = fmaxf(red[tid], red[tid + st]);
        __syncthreads();
    }
    const float mx = red[0];
    __syncthreads();
    float ls = 0.f;
    for (int n = tid; n < NPTS; n += 256) {
        const float p = __expf(s[b * NPTS + n] - mx);
        s[b * NPTS + n] = p;
        ls += p;
    }
    red[tid] = ls;
    __syncthreads();
    for (int st = 128; st > 0; st >>= 1) {
        if (tid < st) red[tid] += red[tid + st];
        __syncthreads();
    }
    const float inv = 1.f / red[0];
    __syncthreads();
    for (int n = tid; n < NPTS; n += 256) s[b * NPTS + n] *= inv;
}

// ---------------- weighted pooling ----------------
__global__ __launch_bounds__(256) void pool_kernel(const float* __restrict__ h,
                                                   const float* __restrict__ w,
                                                   float* __restrict__ pooled) {
    const int c = blockIdx.x, b = blockIdx.y, tid = threadIdx.x;
    __shared__ float red[256];
    const float* hp = h + ((size_t)b * 256 + c) * NPTS;
    const float* wp = w + (size_t)b * NPTS;
    float acc = 0.f;
    for (int n = tid; n < NPTS; n += 256) acc = fmaf(hp[n], wp[n], acc);
    red[tid] = acc;
    __syncthreads();
    for (int st = 128; st > 0; st >>= 1) {
        if (tid < st) red[tid] += red[tid + st];
        __syncthreads();
    }
    if (tid == 0) pooled[b * 256 + c] = red[0];
}

// ---------------- final FC + ReLU ----------------
__global__ __launch_bounds__(256) void fc_kernel(const float* __restrict__ pooled,
                                                 const float* __restrict__ fcw,
                                                 const float* __restrict__ fcb,
                                                 float* __restrict__ out) {
    const int b = blockIdx.x, j = threadIdx.x;
    __shared__ float ps[256];
    ps[j] = pooled[b * 256 + j];
    __syncthreads();
    float acc = fcb[j];
    for (int c = 0; c < 256; ++c) acc = fmaf(ps[c], fcw[j * 256 + c], acc);
    out[b * 256 + j] = fmaxf(acc, 0.f);
}

extern "C" void kernel_launch(void* const* d_in, const int* in_sizes, int n_in,
                              void* d_out, int out_size, void* d_ws, size_t ws_size,
                              hipStream_t stream) {
    const float* x   = (const float*)d_in[0];
    const float* w1  = (const float*)d_in[1];
    const float* b1  = (const float*)d_in[2];
    const float* g1  = (const float*)d_in[3];
    const float* be1 = (const float*)d_in[4];
    const float* w2  = (const float*)d_in[5];
    const float* b2  = (const float*)d_in[6];
    const float* g2  = (const float*)d_in[7];
    const float* be2 = (const float*)d_in[8];
    const float* w3  = (const float*)d_in[9];
    const float* b3  = (const float*)d_in[10];
    const float* g3  = (const float*)d_in[11];
    const float* be3 = (const float*)d_in[12];
    const float* qw  = (const float*)d_in[13];
    const float* qb  = (const float*)d_in[14];
    const float* kw  = (const float*)d_in[15];
    const float* kb  = (const float*)d_in[16];
    const float* vw  = (const float*)d_in[17];
    const float* vb  = (const float*)d_in[18];
    const float* fw  = (const float*)d_in[19];
    const float* fb  = (const float*)d_in[20];
    const float* aw1 = (const float*)d_in[21];
    const float* ab1 = (const float*)d_in[22];
    const float* aw2 = (const float*)d_in[23];
    const float* ab2 = (const float*)d_in[24];
    const float* fcw = (const float*)d_in[25];
    const float* fcb = (const float*)d_in[26];

    float* ws = (float*)d_ws;
    float* h0 = ws;                     // 4*18*4096   (aliased later: M/L arrays)
    float* h1 = h0 + 294912;            // 4*64*4096   (aliased later: Acc1)
    float* h2 = h1 + 1048576;           // 4*128*4096
    float* h3 = h2 + 2097152;           // 4*256*4096
    float* Q  = h3 + 4194304;           // bf16 [B][N][128]
    float* K  = Q  + 2097152;
    float* V  = K  + 2097152;
    float* Oa = V  + 2097152;           // f32 [B][128][N] = Acc0 / combined O
    float* h4 = Oa + 2097152;
    float* a  = h4 + 4194304;
    float* s  = a  + 1048576;
    float* pooled = s + 16384;
    float* mean   = pooled + 1024;
    float* istd   = mean + 256;
    float4* xyzw  = (float4*)(istd + 256);   // B*NPTS float4

    unsigned short* Qb = (unsigned short*)Q;
    unsigned short* Kb = (unsigned short*)K;
    unsigned short* Vb = (unsigned short*)V;

    float* Acc1 = h1;
    float* M0   = h0;
    float* L0   = h0 + 16384;
    float* M1   = h0 + 32768;
    float* L1   = h0 + 49152;

    pack_kernel<<<dim3(B * NPTS / 256), 256, 0, stream>>>(x, xyzw);
    knn3_kernel<<<dim3(B * NPTS / 8), 256, 0, stream>>>(x, xyzw, h0);

    // layer 1: 18 -> 64
    conv_kernel<0, false, false><<<dim3(NPTS / 64, 4, B), 256, 0, stream>>>(h0, w1, b1, nullptr, h1, C0, 64);
    bn_stats_kernel<<<64, 256, 0, stream>>>(h1, mean, istd, 64);
    bn_relu_kernel<<<2048, 256, 0, stream>>>(h1, g1, be1, mean, istd, 64);
    // layer 2: 64 -> 128
    conv_kernel<0, false, false><<<dim3(NPTS / 64, 8, B), 256, 0, stream>>>(h1, w2, b2, nullptr, h2, 64, 128);
    bn_stats_kernel<<<128, 256, 0, stream>>>(h2, mean, istd, 128);
    bn_relu_kernel<<<2048, 256, 0, stream>>>(h2, g2, be2, mean, istd, 128);
    // layer 3: 128 -> 256
    conv_kernel<0, false, false><<<dim3(NPTS / 64, 16, B), 256, 0, stream>>>(h2, w3, b3, nullptr, h3, 128, 256);
    bn_stats_kernel<<<256, 256, 0, stream>>>(h3, mean, istd, 256);
    bn_relu_kernel<<<2048, 256, 0, stream>>>(h3, g3, be3, mean, istd, 256);

    // Q, K projections -> bf16 [n][h]; V -> bf16 [h][n]
    conv_kernel<1, false, false><<<dim3(NPTS / 64, 8, B), 256, 0, stream>>>(h3, qw, qb, nullptr, Qb, 256, 128);
    conv_kernel<1, false, false><<<dim3(NPTS / 64, 8, B), 256, 0, stream>>>(h3, kw, kb, nullptr, Kb, 256, 128);
    conv_kernel<2, false, false><<<dim3(NPTS / 64, 8, B), 256, 0, stream>>>(h3, vw, vb, nullptr, Vb, 256, 128);

    fmha2_kernel<<<dim3(NPTS / QR, B, 2), 256, 0, stream>>>(Qb, Kb, Vb, Oa, Acc1, M0, L0, M1, L1);
    fmha_combine_kernel<<<dim3(B * HID * NPTS / 256), 256, 0, stream>>>(Oa, Acc1, M0, L0, M1, L1);

    // fuse-out conv + residual: 128 -> 256, + h3
    conv_kernel<0, false, true><<<dim3(NPTS / 64, 16, B), 256, 0, stream>>>(Oa, fw, fb, h3, h4, 128, 256);
    // attention-pool MLP
    conv_kernel<0, true, false><<<dim3(NPTS / 64, 4, B), 256, 0, stream>>>(h4, aw1, ab1, nullptr, a, 256, 64);
    conv_kernel<0, false, false><<<dim3(NPTS / 64, 1, B), 256, 0, stream>>>(a, aw2, ab2, nullptr, s, 64, 1);

    softmax_w_kernel<<<B, 256, 0, stream>>>(s);
    pool_kernel<<<dim3(256, B), 256, 0, stream>>>(h4, s, pooled);
    fc_kernel<<<B, 256, 0, stream>>>(pooled, fcw, fcb, (float*)d_out);

    (void)in_sizes; (void)n_in; (void)out_size; (void)ws_size;
}